// Round 1
// baseline (502.653 us; speedup 1.0000x reference)
//
#include <hip/hip_runtime.h>
#include <hip/hip_bf16.h>
#include <math.h>

#define DEVI __device__ __forceinline__

typedef __attribute__((ext_vector_type(8))) short bf16x8;
typedef __attribute__((ext_vector_type(4))) float f32x4;

DEVI unsigned short f2bf(float f) {
    union { float f; unsigned u; } v; v.f = f;
    unsigned r = v.u + 0x7FFFu + ((v.u >> 16) & 1u);
    return (unsigned short)(r >> 16);
}

DEVI void gload16(const void* g, void* l) {
    __builtin_amdgcn_global_load_lds((const __attribute__((address_space(1))) void*)g,
                                     (__attribute__((address_space(3))) void*)l, 16, 0, 0);
}

// ---------------- weight fake-quant + bf16 convert ----------------
__global__ __launch_bounds__(256) void quant_kernel(
    const float* __restrict__ W, const float* __restrict__ e, const float* __restrict__ b,
    unsigned short* __restrict__ out, int total, int lgK)
{
    for (int i = blockIdx.x * blockDim.x + threadIdx.x; i < total; i += gridDim.x * blockDim.x) {
        int n = i >> lgK;
        float ev = e[n], bv = b[n];
        float br = fmaxf(bv, 0.f);
        float mn, mx;
        if (br > 0.f) { float p = exp2f(br - 1.f); mn = -p; mx = p - 1.f; }
        else          { mn = 0.f; mx = 0.f; }
        float qw = fminf(fmaxf(exp2f(-ev) * W[i], mn), mx);
        out[i] = f2bf(exp2f(ev) * rintf(qw));
    }
}

// ---------------- LayerNorm: fp32 in -> bf16 out ----------------
__global__ __launch_bounds__(256) void ln_kernel(
    const float* __restrict__ x, const float* __restrict__ g, const float* __restrict__ be,
    unsigned short* __restrict__ out)
{
    int row = blockIdx.x;
    union { float4 v4; float a[4]; } v;
    v.v4 = ((const float4*)(x + (size_t)row * 1024))[threadIdx.x];
    float s = v.a[0] + v.a[1] + v.a[2] + v.a[3];
    float s2 = v.a[0]*v.a[0] + v.a[1]*v.a[1] + v.a[2]*v.a[2] + v.a[3]*v.a[3];
    #pragma unroll
    for (int off = 32; off > 0; off >>= 1) { s += __shfl_down(s, off); s2 += __shfl_down(s2, off); }
    __shared__ float ps[4], ps2[4];
    int wave = threadIdx.x >> 6, lane = threadIdx.x & 63;
    if (lane == 0) { ps[wave] = s; ps2[wave] = s2; }
    __syncthreads();
    float mu = (ps[0] + ps[1] + ps[2] + ps[3]) * (1.0f / 1024.0f);
    float var = (ps2[0] + ps2[1] + ps2[2] + ps2[3]) * (1.0f / 1024.0f) - mu * mu;
    float rs = rsqrtf(var + 1e-5f);
    int c = threadIdx.x * 4;
    union { unsigned short u[4]; unsigned long long ll; } o;
    #pragma unroll
    for (int j = 0; j < 4; j++) o.u[j] = f2bf((v.a[j] - mu) * rs * g[c + j] + be[c + j]);
    *(unsigned long long*)(out + (size_t)row * 1024 + c) = o.ll;
}

// ---------------- GEMM: C[M,N] = A[M,K] * B[N,K]^T, m97 structure ----------------
// EP 0: out bf16 plain.  EP 1: outf = acc + bias[n] + res[m,n] (fp32).  EP 2: outb = relu(acc + bias[n]) bf16.
template<int EP>
__global__ __launch_bounds__(256) void gemm_bt(
    const unsigned short* __restrict__ A, const unsigned short* __restrict__ Bw,
    int N, int K,
    const float* __restrict__ bias, const float* __restrict__ res,
    float* __restrict__ outf, unsigned short* __restrict__ outb)
{
    __shared__ __align__(16) unsigned short As[128 * 32];
    __shared__ __align__(16) unsigned short Bs[128 * 32];
    int tid = threadIdx.x, lane = tid & 63, wave = tid >> 6;
    int brow = blockIdx.y * 128, bcol = blockIdx.x * 128;
    int wr = wave >> 1, wc = wave & 1;
    int r = lane & 15, g4 = lane >> 4;
    f32x4 acc[4][4];
    #pragma unroll
    for (int i = 0; i < 4; i++)
        #pragma unroll
        for (int j = 0; j < 4; j++) acc[i][j] = (f32x4){0.f, 0.f, 0.f, 0.f};

    for (int k0 = 0; k0 < K; k0 += 32) {
        __syncthreads();
        #pragma unroll
        for (int half = 0; half < 2; half++) {
            int idx = half * 256 + tid;             // 0..511: row = idx>>2, colblock = idx&3
            gload16(A  + (size_t)(brow + (idx >> 2)) * K + k0 + (idx & 3) * 8, As + idx * 8);
            gload16(Bw + (size_t)(bcol + (idx >> 2)) * K + k0 + (idx & 3) * 8, Bs + idx * 8);
        }
        __syncthreads();
        bf16x8 af[4], bfr[4];
        #pragma unroll
        for (int mi = 0; mi < 4; mi++) af[mi]  = *(const bf16x8*)&As[(wr * 64 + mi * 16 + r) * 32 + g4 * 8];
        #pragma unroll
        for (int ni = 0; ni < 4; ni++) bfr[ni] = *(const bf16x8*)&Bs[(wc * 64 + ni * 16 + r) * 32 + g4 * 8];
        #pragma unroll
        for (int mi = 0; mi < 4; mi++)
            #pragma unroll
            for (int ni = 0; ni < 4; ni++)
                acc[mi][ni] = __builtin_amdgcn_mfma_f32_16x16x32_bf16(af[mi], bfr[ni], acc[mi][ni], 0, 0, 0);
    }

    #pragma unroll
    for (int mi = 0; mi < 4; mi++)
        #pragma unroll
        for (int ni = 0; ni < 4; ni++)
            #pragma unroll
            for (int i = 0; i < 4; i++) {
                int row = brow + wr * 64 + mi * 16 + g4 * 4 + i;
                int col = bcol + wc * 64 + ni * 16 + r;
                float v = acc[mi][ni][i];
                if (EP == 0) {
                    outb[(size_t)row * N + col] = f2bf(v);
                } else if (EP == 1) {
                    outf[(size_t)row * N + col] = v + bias[col] + res[(size_t)row * N + col];
                } else {
                    outb[(size_t)row * N + col] = f2bf(fmaxf(v + bias[col], 0.f));
                }
            }
}

// ---------------- Flash attention (causal), per (b,h) x 64-row Q-tile ----------------
__global__ __launch_bounds__(256) void attn_kernel(
    const unsigned short* __restrict__ qkv, unsigned short* __restrict__ att)
{
    __shared__ __align__(16) unsigned short Ks[64 * 64];
    __shared__ __align__(16) unsigned short Vt[64 * 64];   // Vt[d][s], swizzled
    __shared__ __align__(16) unsigned short Ps[64 * 64];   // P[t][s], swizzled
    int tid = threadIdx.x, lane = tid & 63, wave = tid >> 6;
    int qi = blockIdx.x;
    int bh = blockIdx.y, bb = bh >> 4, hh = bh & 15;
    int q0 = qi * 64;
    int r = lane & 15, g4 = lane >> 4;
    const unsigned short* base = qkv + (size_t)bb * 1024 * 3072;

    // Q fragments (held in regs the whole kernel)
    bf16x8 qf[2];
    int qrow = q0 + wave * 16 + r;
    #pragma unroll
    for (int kk = 0; kk < 2; kk++)
        qf[kk] = *(const bf16x8*)&base[(size_t)qrow * 3072 + hh * 64 + kk * 32 + g4 * 8];

    f32x4 oacc[4];
    #pragma unroll
    for (int i = 0; i < 4; i++) oacc[i] = (f32x4){0.f, 0.f, 0.f, 0.f};
    float m_i[4] = {-INFINITY, -INFINITY, -INFINITY, -INFINITY};
    float l_i[4] = {0.f, 0.f, 0.f, 0.f};

    for (int ki = 0; ki <= qi; ki++) {
        int k0 = ki * 64;
        __syncthreads();
        // stage K tile (swizzled source -> linear LDS dest)
        #pragma unroll
        for (int half = 0; half < 2; half++) {
            int idx = half * 256 + tid;           // row = idx>>3 (0..63), slot = idx&7
            int row = idx >> 3, slot = idx & 7;
            int gs = slot ^ (row & 7);
            gload16(base + (size_t)(k0 + row) * 3072 + 1024 + hh * 64 + gs * 8, Ks + idx * 8);
        }
        // stage V^T (reg-staged transpose; coalesced 2B column reads)
        {
            int d = tid & 63, sb = tid >> 6;
            unsigned short tmp[16];
            #pragma unroll
            for (int i2 = 0; i2 < 16; i2++)
                tmp[i2] = base[(size_t)(k0 + sb * 16 + i2) * 3072 + 2048 + hh * 64 + d];
            union { unsigned short u[8]; bf16x8 v; } w0, w1;
            #pragma unroll
            for (int i2 = 0; i2 < 8; i2++) { w0.u[i2] = tmp[i2]; w1.u[i2] = tmp[8 + i2]; }
            int s0 = (sb * 2) ^ (d & 7), s1 = (sb * 2 + 1) ^ (d & 7);
            *(bf16x8*)&Vt[d * 64 + s0 * 8] = w0.v;
            *(bf16x8*)&Vt[d * 64 + s1 * 8] = w1.v;
        }
        __syncthreads();

        // S = Q K^T
        f32x4 sacc[4];
        #pragma unroll
        for (int c4 = 0; c4 < 4; c4++) sacc[c4] = (f32x4){0.f, 0.f, 0.f, 0.f};
        #pragma unroll
        for (int c4 = 0; c4 < 4; c4++) {
            int krow = c4 * 16 + r;
            #pragma unroll
            for (int kk = 0; kk < 2; kk++) {
                int slot = (g4 + kk * 4) ^ (krow & 7);
                bf16x8 kf = *(const bf16x8*)&Ks[krow * 64 + slot * 8];
                sacc[c4] = __builtin_amdgcn_mfma_f32_16x16x32_bf16(qf[kk], kf, sacc[c4], 0, 0, 0);
            }
        }
        // scale + causal mask
        float pv[4][4];
        bool diag = (ki == qi);
        #pragma unroll
        for (int c4 = 0; c4 < 4; c4++)
            #pragma unroll
            for (int i = 0; i < 4; i++) {
                float sv = sacc[c4][i] * 0.03125f;
                if (diag && (k0 + c4 * 16 + r) > (q0 + wave * 16 + g4 * 4 + i)) sv = -INFINITY;
                pv[c4][i] = sv;
            }
        // online softmax per row (rows live across 16-lane groups)
        #pragma unroll
        for (int i = 0; i < 4; i++) {
            float tm = fmaxf(fmaxf(pv[0][i], pv[1][i]), fmaxf(pv[2][i], pv[3][i]));
            tm = fmaxf(tm, __shfl_xor(tm, 1));
            tm = fmaxf(tm, __shfl_xor(tm, 2));
            tm = fmaxf(tm, __shfl_xor(tm, 4));
            tm = fmaxf(tm, __shfl_xor(tm, 8));
            float mn = fmaxf(m_i[i], tm);
            float fs = __expf(m_i[i] - mn);
            m_i[i] = mn;
            float rowsum = 0.f;
            #pragma unroll
            for (int c4 = 0; c4 < 4; c4++) {
                float p = __expf(pv[c4][i] - mn);
                pv[c4][i] = p;
                rowsum += p;
            }
            rowsum += __shfl_xor(rowsum, 1);
            rowsum += __shfl_xor(rowsum, 2);
            rowsum += __shfl_xor(rowsum, 4);
            rowsum += __shfl_xor(rowsum, 8);
            l_i[i] = l_i[i] * fs + rowsum;
            #pragma unroll
            for (int n4 = 0; n4 < 4; n4++) oacc[n4][i] *= fs;
            // write P row slice to LDS (D-layout -> A-layout round trip), swizzled
            int tl = wave * 16 + g4 * 4 + i;
            #pragma unroll
            for (int c4 = 0; c4 < 4; c4++) {
                int s = c4 * 16 + r;
                Ps[tl * 64 + (((s >> 3) ^ (tl & 7)) << 3) + (s & 7)] = f2bf(pv[c4][i]);
            }
        }
        // O += P * V   (A = P from LDS, B = Vt rows = d)
        #pragma unroll
        for (int ks = 0; ks < 2; ks++) {
            int tl2 = wave * 16 + r;
            int sb8 = ks * 4 + g4;
            bf16x8 pa = *(const bf16x8*)&Ps[tl2 * 64 + ((sb8 ^ (tl2 & 7)) << 3)];
            #pragma unroll
            for (int n4 = 0; n4 < 4; n4++) {
                int d = n4 * 16 + r;
                bf16x8 vf = *(const bf16x8*)&Vt[d * 64 + (((ks * 4 + g4) ^ (d & 7)) << 3)];
                oacc[n4] = __builtin_amdgcn_mfma_f32_16x16x32_bf16(pa, vf, oacc[n4], 0, 0, 0);
            }
        }
    }

    // write O (bf16) into att[b, t, h*64+d]
    #pragma unroll
    for (int i = 0; i < 4; i++) {
        float inv = 1.f / l_i[i];
        int trow = q0 + wave * 16 + g4 * 4 + i;
        #pragma unroll
        for (int n4 = 0; n4 < 4; n4++)
            att[((size_t)(bb * 1024 + trow)) * 1024 + hh * 64 + n4 * 16 + r] = f2bf(oacc[n4][i] * inv);
    }
}

// ---------------- host ----------------
extern "C" void kernel_launch(void* const* d_in, const int* in_sizes, int n_in,
                              void* d_out, int out_size, void* d_ws, size_t ws_size,
                              hipStream_t stream)
{
    const float* x     = (const float*)d_in[0];
    const float* Wq    = (const float*)d_in[1];
    const float* Wk    = (const float*)d_in[2];
    const float* Wv    = (const float*)d_in[3];
    const float* eq    = (const float*)d_in[4];
    const float* bq    = (const float*)d_in[5];
    const float* ek    = (const float*)d_in[6];
    const float* bk    = (const float*)d_in[7];
    const float* ev    = (const float*)d_in[8];
    const float* bv    = (const float*)d_in[9];
    const float* Wp    = (const float*)d_in[10];
    const float* ep    = (const float*)d_in[11];
    const float* bp    = (const float*)d_in[12];
    const float* biasp = (const float*)d_in[13];
    const float* W1    = (const float*)d_in[14];
    const float* e1    = (const float*)d_in[15];
    const float* b1    = (const float*)d_in[16];
    const float* bias1 = (const float*)d_in[17];
    const float* W2    = (const float*)d_in[18];
    const float* e2    = (const float*)d_in[19];
    const float* b2    = (const float*)d_in[20];
    const float* bias2 = (const float*)d_in[21];
    const float* g1    = (const float*)d_in[22];
    const float* be1   = (const float*)d_in[23];
    const float* g2    = (const float*)d_in[24];
    const float* be2   = (const float*)d_in[25];

    const size_t MB = 1ull << 20;
    char* ws = (char*)d_ws;
    unsigned short* Wqkvq = (unsigned short*)(ws);            //  6 MB: [3072,1024] bf16
    unsigned short* Wpq   = (unsigned short*)(ws + 6 * MB);   //  2 MB
    unsigned short* W1q   = (unsigned short*)(ws + 8 * MB);   //  8 MB
    unsigned short* W2q   = (unsigned short*)(ws + 16 * MB);  //  8 MB
    unsigned short* hbuf  = (unsigned short*)(ws + 24 * MB);  // 16 MB (h, then h2)
    unsigned short* qkvb  = (unsigned short*)(ws + 40 * MB);  // 48 MB [8192,3072]; later f [8192,4096] (64 MB)
    unsigned short* fbuf  = qkvb;
    unsigned short* attb  = (unsigned short*)(ws + 88 * MB);  // 16 MB
    float*          x2    = (float*)(ws + 104 * MB);          // 32 MB -> total 136 MB

    // weight fake-quant -> bf16
    quant_kernel<<<2048, 256, 0, stream>>>(Wq, eq, bq, Wqkvq,               1024 * 1024, 10);
    quant_kernel<<<2048, 256, 0, stream>>>(Wk, ek, bk, Wqkvq + 1024 * 1024, 1024 * 1024, 10);
    quant_kernel<<<2048, 256, 0, stream>>>(Wv, ev, bv, Wqkvq + 2048 * 1024, 1024 * 1024, 10);
    quant_kernel<<<2048, 256, 0, stream>>>(Wp, ep, bp, Wpq,                 1024 * 1024, 10);
    quant_kernel<<<2048, 256, 0, stream>>>(W1, e1, b1, W1q,                 4096 * 1024, 10);
    quant_kernel<<<2048, 256, 0, stream>>>(W2, e2, b2, W2q,                 1024 * 4096, 12);

    // LN1: x -> h (bf16)
    ln_kernel<<<8192, 256, 0, stream>>>(x, g1, be1, hbuf);
    // QKV: [8192,3072] bf16
    gemm_bt<0><<<dim3(24, 64), 256, 0, stream>>>(hbuf, Wqkvq, 3072, 1024, nullptr, nullptr, nullptr, qkvb);
    // attention
    attn_kernel<<<dim3(16, 128), 256, 0, stream>>>(qkvb, attb);
    // proj + bias + residual -> x2 (fp32)
    gemm_bt<1><<<dim3(8, 64), 256, 0, stream>>>(attb, Wpq, 1024, 1024, biasp, x, x2, nullptr);
    // LN2: x2 -> h2 (bf16, reuse hbuf)
    ln_kernel<<<8192, 256, 0, stream>>>(x2, g2, be2, hbuf);
    // FFN1: relu(h2 W1^T + b1) -> f (bf16)
    gemm_bt<2><<<dim3(32, 64), 256, 0, stream>>>(hbuf, W1q, 4096, 1024, bias1, nullptr, nullptr, fbuf);
    // FFN2: f W2^T + b2 + x2 -> out (fp32)
    gemm_bt<1><<<dim3(8, 64), 256, 0, stream>>>(fbuf, W2q, 1024, 4096, bias2, x2, (float*)d_out, nullptr);
}

// Round 3
// 441.673 us; speedup vs baseline: 1.1381x; 1.1381x over previous
//
#include <hip/hip_runtime.h>
#include <hip/hip_bf16.h>
#include <math.h>

#define DEVI __device__ __forceinline__

typedef __attribute__((ext_vector_type(8))) short bf16x8;
typedef __attribute__((ext_vector_type(4))) float f32x4;

DEVI unsigned short f2bf(float f) {
    union { float f; unsigned u; } v; v.f = f;
    unsigned r = v.u + 0x7FFFu + ((v.u >> 16) & 1u);
    return (unsigned short)(r >> 16);
}

DEVI void gload16(const void* g, void* l) {
    __builtin_amdgcn_global_load_lds((const __attribute__((address_space(1))) void*)g,
                                     (__attribute__((address_space(3))) void*)l, 16, 0, 0);
}

// ---------------- weight fake-quant + bf16 convert ----------------
__global__ __launch_bounds__(256) void quant_kernel(
    const float* __restrict__ W, const float* __restrict__ e, const float* __restrict__ b,
    unsigned short* __restrict__ out, int total, int lgK)
{
    for (int i = blockIdx.x * blockDim.x + threadIdx.x; i < total; i += gridDim.x * blockDim.x) {
        int n = i >> lgK;
        float ev = e[n], bv = b[n];
        float br = fmaxf(bv, 0.f);
        float mn, mx;
        if (br > 0.f) { float p = exp2f(br - 1.f); mn = -p; mx = p - 1.f; }
        else          { mn = 0.f; mx = 0.f; }
        float qw = fminf(fmaxf(exp2f(-ev) * W[i], mn), mx);
        out[i] = f2bf(exp2f(ev) * rintf(qw));
    }
}

// ---------------- LayerNorm: fp32 in -> bf16 out ----------------
__global__ __launch_bounds__(256) void ln_kernel(
    const float* __restrict__ x, const float* __restrict__ g, const float* __restrict__ be,
    unsigned short* __restrict__ out)
{
    int row = blockIdx.x;
    union { float4 v4; float a[4]; } v;
    v.v4 = ((const float4*)(x + (size_t)row * 1024))[threadIdx.x];
    float s = v.a[0] + v.a[1] + v.a[2] + v.a[3];
    float s2 = v.a[0]*v.a[0] + v.a[1]*v.a[1] + v.a[2]*v.a[2] + v.a[3]*v.a[3];
    #pragma unroll
    for (int off = 32; off > 0; off >>= 1) { s += __shfl_down(s, off); s2 += __shfl_down(s2, off); }
    __shared__ float ps[4], ps2[4];
    int wave = threadIdx.x >> 6, lane = threadIdx.x & 63;
    if (lane == 0) { ps[wave] = s; ps2[wave] = s2; }
    __syncthreads();
    float mu = (ps[0] + ps[1] + ps[2] + ps[3]) * (1.0f / 1024.0f);
    float var = (ps2[0] + ps2[1] + ps2[2] + ps2[3]) * (1.0f / 1024.0f) - mu * mu;
    float rs = rsqrtf(var + 1e-5f);
    int c = threadIdx.x * 4;
    union { unsigned short u[4]; unsigned long long ll; } o;
    #pragma unroll
    for (int j = 0; j < 4; j++) o.u[j] = f2bf((v.a[j] - mu) * rs * g[c + j] + be[c + j]);
    *(unsigned long long*)(out + (size_t)row * 1024 + c) = o.ll;
}

// ---------------- GEMM 128x128 (m97 structure, race-free), XCD-swizzled ----------------
// EP 0: out bf16. EP 1: outf = acc + bias[n] + res[m,n] (fp32). EP 2: outb = relu(acc+bias) bf16.
template<int EP>
__global__ __launch_bounds__(256) void gemm_bt(
    const unsigned short* __restrict__ A, const unsigned short* __restrict__ Bw,
    int N, int K,
    const float* __restrict__ bias, const float* __restrict__ res,
    float* __restrict__ outf, unsigned short* __restrict__ outb)
{
    __shared__ __align__(16) unsigned short As[128 * 32];
    __shared__ __align__(16) unsigned short Bs[128 * 32];
    int tid = threadIdx.x, lane = tid & 63, wave = tid >> 6;
    // T1: XCD-aware bijective swizzle (nwg % 8 == 0 for all launch configs here)
    int gx = gridDim.x;
    int nwg = gx * gridDim.y;
    int id = blockIdx.y * gx + blockIdx.x;
    int swz = (id & 7) * (nwg >> 3) + (id >> 3);
    int brow = (swz / gx) * 128, bcol = (swz % gx) * 128;
    int wr = wave >> 1, wc = wave & 1;
    int r = lane & 15, g4 = lane >> 4;
    f32x4 acc[4][4];
    #pragma unroll
    for (int i = 0; i < 4; i++)
        #pragma unroll
        for (int j = 0; j < 4; j++) acc[i][j] = (f32x4){0.f, 0.f, 0.f, 0.f};

    for (int k0 = 0; k0 < K; k0 += 32) {
        __syncthreads();
        #pragma unroll
        for (int half = 0; half < 2; half++) {
            int idx = half * 256 + tid;
            gload16(A  + (size_t)(brow + (idx >> 2)) * K + k0 + (idx & 3) * 8, As + idx * 8);
            gload16(Bw + (size_t)(bcol + (idx >> 2)) * K + k0 + (idx & 3) * 8, Bs + idx * 8);
        }
        __syncthreads();
        bf16x8 af[4], bfr[4];
        #pragma unroll
        for (int mi = 0; mi < 4; mi++) af[mi]  = *(const bf16x8*)&As[(wr * 64 + mi * 16 + r) * 32 + g4 * 8];
        #pragma unroll
        for (int ni = 0; ni < 4; ni++) bfr[ni] = *(const bf16x8*)&Bs[(wc * 64 + ni * 16 + r) * 32 + g4 * 8];
        #pragma unroll
        for (int mi = 0; mi < 4; mi++)
            #pragma unroll
            for (int ni = 0; ni < 4; ni++)
                acc[mi][ni] = __builtin_amdgcn_mfma_f32_16x16x32_bf16(af[mi], bfr[ni], acc[mi][ni], 0, 0, 0);
    }

    #pragma unroll
    for (int mi = 0; mi < 4; mi++)
        #pragma unroll
        for (int ni = 0; ni < 4; ni++)
            #pragma unroll
            for (int i = 0; i < 4; i++) {
                int row = brow + wr * 64 + mi * 16 + g4 * 4 + i;
                int col = bcol + wc * 64 + ni * 16 + r;
                float v = acc[mi][ni][i];
                if (EP == 0) {
                    outb[(size_t)row * N + col] = f2bf(v);
                } else if (EP == 1) {
                    outf[(size_t)row * N + col] = v + bias[col] + res[(size_t)row * N + col];
                } else {
                    outb[(size_t)row * N + col] = f2bf(fmaxf(v + bias[col], 0.f));
                }
            }
}

// ---------------- Flash attention (causal), paired q-tiles for balance ----------------
__global__ __launch_bounds__(256) void attn_kernel(
    const unsigned short* __restrict__ qkv, unsigned short* __restrict__ att)
{
    __shared__ __align__(16) unsigned short Ks[64 * 64];
    __shared__ __align__(16) unsigned short Vt[64 * 64];
    __shared__ __align__(16) unsigned short Ps[64 * 64];
    int tid = threadIdx.x, lane = tid & 63, wave = tid >> 6;
    int pi = blockIdx.x;
    int bh = blockIdx.y, bb = bh >> 4, hh = bh & 15;
    int r = lane & 15, g4 = lane >> 4;
    const unsigned short* base = qkv + (size_t)bb * 1024 * 3072;
    const float SCL = 0.03125f * 1.4426950408889634f;   // (1/32) * log2(e)

    #pragma unroll
    for (int sub = 0; sub < 2; sub++) {
        int qi = sub ? (15 - pi) : pi;
        int q0 = qi * 64;

        bf16x8 qf[2];
        int qrow = q0 + wave * 16 + r;
        #pragma unroll
        for (int kk = 0; kk < 2; kk++)
            qf[kk] = *(const bf16x8*)&base[(size_t)qrow * 3072 + hh * 64 + kk * 32 + g4 * 8];

        f32x4 oacc[4];
        #pragma unroll
        for (int i = 0; i < 4; i++) oacc[i] = (f32x4){0.f, 0.f, 0.f, 0.f};
        float m_i[4] = {-INFINITY, -INFINITY, -INFINITY, -INFINITY};
        float l_i[4] = {0.f, 0.f, 0.f, 0.f};

        for (int ki = 0; ki <= qi; ki++) {
            int k0 = ki * 64;
            __syncthreads();
            #pragma unroll
            for (int half = 0; half < 2; half++) {
                int idx = half * 256 + tid;
                int row = idx >> 3, slot = idx & 7;
                int gs = slot ^ (row & 7);
                gload16(base + (size_t)(k0 + row) * 3072 + 1024 + hh * 64 + gs * 8, Ks + idx * 8);
            }
            {
                int d = tid & 63, sb = tid >> 6;
                unsigned short tmp[16];
                #pragma unroll
                for (int i2 = 0; i2 < 16; i2++)
                    tmp[i2] = base[(size_t)(k0 + sb * 16 + i2) * 3072 + 2048 + hh * 64 + d];
                union { unsigned short u[8]; bf16x8 v; } w0, w1;
                #pragma unroll
                for (int i2 = 0; i2 < 8; i2++) { w0.u[i2] = tmp[i2]; w1.u[i2] = tmp[8 + i2]; }
                int s0 = (sb * 2) ^ (d & 7), s1 = (sb * 2 + 1) ^ (d & 7);
                *(bf16x8*)&Vt[d * 64 + s0 * 8] = w0.v;
                *(bf16x8*)&Vt[d * 64 + s1 * 8] = w1.v;
            }
            __syncthreads();

            f32x4 sacc[4];
            #pragma unroll
            for (int c4 = 0; c4 < 4; c4++) sacc[c4] = (f32x4){0.f, 0.f, 0.f, 0.f};
            #pragma unroll
            for (int c4 = 0; c4 < 4; c4++) {
                int krow = c4 * 16 + r;
                #pragma unroll
                for (int kk = 0; kk < 2; kk++) {
                    int slot = (g4 + kk * 4) ^ (krow & 7);
                    bf16x8 kf = *(const bf16x8*)&Ks[krow * 64 + slot * 8];
                    sacc[c4] = __builtin_amdgcn_mfma_f32_16x16x32_bf16(qf[kk], kf, sacc[c4], 0, 0, 0);
                }
            }
            float pv[4][4];
            bool diag = (ki == qi);
            #pragma unroll
            for (int c4 = 0; c4 < 4; c4++)
                #pragma unroll
                for (int i = 0; i < 4; i++) {
                    float sv = sacc[c4][i] * SCL;
                    if (diag && (k0 + c4 * 16 + r) > (q0 + wave * 16 + g4 * 4 + i)) sv = -INFINITY;
                    pv[c4][i] = sv;
                }
            #pragma unroll
            for (int i = 0; i < 4; i++) {
                float tm = fmaxf(fmaxf(pv[0][i], pv[1][i]), fmaxf(pv[2][i], pv[3][i]));
                tm = fmaxf(tm, __shfl_xor(tm, 1));
                tm = fmaxf(tm, __shfl_xor(tm, 2));
                tm = fmaxf(tm, __shfl_xor(tm, 4));
                tm = fmaxf(tm, __shfl_xor(tm, 8));
                float mn = fmaxf(m_i[i], tm);
                float fs = exp2f(m_i[i] - mn);
                m_i[i] = mn;
                float rowsum = 0.f;
                #pragma unroll
                for (int c4 = 0; c4 < 4; c4++) {
                    float p = exp2f(pv[c4][i] - mn);
                    pv[c4][i] = p;
                    rowsum += p;
                }
                rowsum += __shfl_xor(rowsum, 1);
                rowsum += __shfl_xor(rowsum, 2);
                rowsum += __shfl_xor(rowsum, 4);
                rowsum += __shfl_xor(rowsum, 8);
                l_i[i] = l_i[i] * fs + rowsum;
                #pragma unroll
                for (int n4 = 0; n4 < 4; n4++) oacc[n4][i] *= fs;
                int tl = wave * 16 + g4 * 4 + i;
                #pragma unroll
                for (int c4 = 0; c4 < 4; c4++) {
                    int s = c4 * 16 + r;
                    Ps[tl * 64 + (((s >> 3) ^ (tl & 7)) << 3) + (s & 7)] = f2bf(pv[c4][i]);
                }
            }
            #pragma unroll
            for (int ks = 0; ks < 2; ks++) {
                int tl2 = wave * 16 + r;
                int sb8 = ks * 4 + g4;
                bf16x8 pa = *(const bf16x8*)&Ps[tl2 * 64 + ((sb8 ^ (tl2 & 7)) << 3)];
                #pragma unroll
                for (int n4 = 0; n4 < 4; n4++) {
                    int d = n4 * 16 + r;
                    bf16x8 vf = *(const bf16x8*)&Vt[d * 64 + (((ks * 4 + g4) ^ (d & 7)) << 3)];
                    oacc[n4] = __builtin_amdgcn_mfma_f32_16x16x32_bf16(pa, vf, oacc[n4], 0, 0, 0);
                }
            }
        }

        #pragma unroll
        for (int i = 0; i < 4; i++) {
            float inv = 1.f / l_i[i];
            int trow = q0 + wave * 16 + g4 * 4 + i;
            #pragma unroll
            for (int n4 = 0; n4 < 4; n4++)
                att[((size_t)(bb * 1024 + trow)) * 1024 + hh * 64 + n4 * 16 + r] = f2bf(oacc[n4][i] * inv);
        }
        __syncthreads();
    }
}

// ---------------- host ----------------
extern "C" void kernel_launch(void* const* d_in, const int* in_sizes, int n_in,
                              void* d_out, int out_size, void* d_ws, size_t ws_size,
                              hipStream_t stream)
{
    const float* x     = (const float*)d_in[0];
    const float* Wq    = (const float*)d_in[1];
    const float* Wk    = (const float*)d_in[2];
    const float* Wv    = (const float*)d_in[3];
    const float* eq    = (const float*)d_in[4];
    const float* bq    = (const float*)d_in[5];
    const float* ek    = (const float*)d_in[6];
    const float* bk    = (const float*)d_in[7];
    const float* ev    = (const float*)d_in[8];
    const float* bv    = (const float*)d_in[9];
    const float* Wp    = (const float*)d_in[10];
    const float* ep    = (const float*)d_in[11];
    const float* bp    = (const float*)d_in[12];
    const float* biasp = (const float*)d_in[13];
    const float* W1    = (const float*)d_in[14];
    const float* e1    = (const float*)d_in[15];
    const float* b1    = (const float*)d_in[16];
    const float* bias1 = (const float*)d_in[17];
    const float* W2    = (const float*)d_in[18];
    const float* e2    = (const float*)d_in[19];
    const float* b2    = (const float*)d_in[20];
    const float* bias2 = (const float*)d_in[21];
    const float* g1    = (const float*)d_in[22];
    const float* be1   = (const float*)d_in[23];
    const float* g2    = (const float*)d_in[24];
    const float* be2   = (const float*)d_in[25];

    const size_t MB = 1ull << 20;
    char* ws = (char*)d_ws;
    unsigned short* Wqkvq = (unsigned short*)(ws);            //  6 MB
    unsigned short* Wpq   = (unsigned short*)(ws + 6 * MB);   //  2 MB
    unsigned short* W1q   = (unsigned short*)(ws + 8 * MB);   //  8 MB
    unsigned short* W2q   = (unsigned short*)(ws + 16 * MB);  //  8 MB
    unsigned short* hbuf  = (unsigned short*)(ws + 24 * MB);  // 16 MB
    unsigned short* qkvb  = (unsigned short*)(ws + 40 * MB);  // 48 MB; later f (64 MB)
    unsigned short* fbuf  = qkvb;
    unsigned short* attb  = (unsigned short*)(ws + 88 * MB);  // 16 MB
    float*          x2    = (float*)(ws + 104 * MB);          // 32 MB

    quant_kernel<<<2048, 256, 0, stream>>>(Wq, eq, bq, Wqkvq,               1024 * 1024, 10);
    quant_kernel<<<2048, 256, 0, stream>>>(Wk, ek, bk, Wqkvq + 1024 * 1024, 1024 * 1024, 10);
    quant_kernel<<<2048, 256, 0, stream>>>(Wv, ev, bv, Wqkvq + 2048 * 1024, 1024 * 1024, 10);
    quant_kernel<<<2048, 256, 0, stream>>>(Wp, ep, bp, Wpq,                 1024 * 1024, 10);
    quant_kernel<<<2048, 256, 0, stream>>>(W1, e1, b1, W1q,                 4096 * 1024, 10);
    quant_kernel<<<2048, 256, 0, stream>>>(W2, e2, b2, W2q,                 1024 * 4096, 12);

    ln_kernel<<<8192, 256, 0, stream>>>(x, g1, be1, hbuf);
    // QKV: [8192,3072] bf16
    gemm_bt<0><<<dim3(24, 64), 256, 0, stream>>>(hbuf, Wqkvq, 3072, 1024, nullptr, nullptr, nullptr, qkvb);
    // attention (paired q-tiles)
    attn_kernel<<<dim3(8, 128), 256, 0, stream>>>(qkvb, attb);
    // proj + bias + residual -> x2 (fp32)
    gemm_bt<1><<<dim3(8, 64), 256, 0, stream>>>(attb, Wpq, 1024, 1024, biasp, x, x2, nullptr);
    ln_kernel<<<8192, 256, 0, stream>>>(x2, g2, be2, hbuf);
    // FFN1: relu(h2 W1^T + b1) -> f (bf16)
    gemm_bt<2><<<dim3(32, 64), 256, 0, stream>>>(hbuf, W1q, 4096, 1024, bias1, nullptr, nullptr, fbuf);
    // FFN2: f W2^T + b2 + x2 -> out (fp32)
    gemm_bt<1><<<dim3(8, 64), 256, 0, stream>>>(fbuf, W2q, 1024, 4096, bias2, x2, (float*)d_out, nullptr);
}

// Round 4
// 401.647 us; speedup vs baseline: 1.2515x; 1.0997x over previous
//
#include <hip/hip_runtime.h>
#include <hip/hip_bf16.h>
#include <math.h>

#define DEVI __device__ __forceinline__

typedef __attribute__((ext_vector_type(8))) short bf16x8;
typedef __attribute__((ext_vector_type(4))) float f32x4;

DEVI unsigned short f2bf(float f) {
    union { float f; unsigned u; } v; v.f = f;
    unsigned r = v.u + 0x7FFFu + ((v.u >> 16) & 1u);
    return (unsigned short)(r >> 16);
}

DEVI void gload16(const void* g, void* l) {
    __builtin_amdgcn_global_load_lds((const __attribute__((address_space(1))) void*)g,
                                     (__attribute__((address_space(3))) void*)l, 16, 0, 0);
}

// ---------------- fused weight fake-quant (all 6 weights, one dispatch) ----------------
__global__ __launch_bounds__(256) void quant6_kernel(
    const float* __restrict__ Wq, const float* __restrict__ Wk, const float* __restrict__ Wv,
    const float* __restrict__ Wp, const float* __restrict__ W1, const float* __restrict__ W2,
    const float* __restrict__ eq, const float* __restrict__ ek, const float* __restrict__ ev,
    const float* __restrict__ ep, const float* __restrict__ e1, const float* __restrict__ e2,
    const float* __restrict__ bq, const float* __restrict__ bk, const float* __restrict__ bv,
    const float* __restrict__ bp, const float* __restrict__ b1, const float* __restrict__ b2,
    unsigned short* __restrict__ Wqkvq, unsigned short* __restrict__ Wpq,
    unsigned short* __restrict__ W1q, unsigned short* __restrict__ W2q)
{
    const int M1 = 1 << 20;
    const int NCH = 3 * M1;  // 12M elems / 4 per chunk
    for (int c = blockIdx.x * blockDim.x + threadIdx.x; c < NCH; c += gridDim.x * blockDim.x) {
        int elem = c * 4;
        const float *W, *e, *b; unsigned short* o; int lgK, local;
        if (elem < M1)            { W = Wq; e = eq; b = bq; o = Wqkvq;          lgK = 10; local = elem; }
        else if (elem < 2 * M1)   { W = Wk; e = ek; b = bk; o = Wqkvq + M1;     lgK = 10; local = elem - M1; }
        else if (elem < 3 * M1)   { W = Wv; e = ev; b = bv; o = Wqkvq + 2 * M1; lgK = 10; local = elem - 2 * M1; }
        else if (elem < 4 * M1)   { W = Wp; e = ep; b = bp; o = Wpq;            lgK = 10; local = elem - 3 * M1; }
        else if (elem < 8 * M1)   { W = W1; e = e1; b = b1; o = W1q;            lgK = 10; local = elem - 4 * M1; }
        else                      { W = W2; e = e2; b = b2; o = W2q;            lgK = 12; local = elem - 8 * M1; }
        int row = local >> lgK;
        float evv = e[row], bvv = b[row];
        float br = fmaxf(bvv, 0.f);
        float mn, mx;
        if (br > 0.f) { float p = exp2f(br - 1.f); mn = -p; mx = p - 1.f; }
        else          { mn = 0.f; mx = 0.f; }
        float si = exp2f(-evv), so = exp2f(evv);
        union { float4 v4; float a[4]; } v;
        v.v4 = *(const float4*)(W + local);
        union { unsigned short u[4]; unsigned long long ll; } ot;
        #pragma unroll
        for (int j = 0; j < 4; j++) {
            float qw = fminf(fmaxf(si * v.a[j], mn), mx);
            ot.u[j] = f2bf(so * rintf(qw));
        }
        *(unsigned long long*)(o + local) = ot.ll;
    }
}

// ---------------- LayerNorm: fp32 in -> bf16 out ----------------
__global__ __launch_bounds__(256) void ln_kernel(
    const float* __restrict__ x, const float* __restrict__ g, const float* __restrict__ be,
    unsigned short* __restrict__ out)
{
    int row = blockIdx.x;
    union { float4 v4; float a[4]; } v;
    v.v4 = ((const float4*)(x + (size_t)row * 1024))[threadIdx.x];
    float s = v.a[0] + v.a[1] + v.a[2] + v.a[3];
    float s2 = v.a[0]*v.a[0] + v.a[1]*v.a[1] + v.a[2]*v.a[2] + v.a[3]*v.a[3];
    #pragma unroll
    for (int off = 32; off > 0; off >>= 1) { s += __shfl_down(s, off); s2 += __shfl_down(s2, off); }
    __shared__ float ps[4], ps2[4];
    int wave = threadIdx.x >> 6, lane = threadIdx.x & 63;
    if (lane == 0) { ps[wave] = s; ps2[wave] = s2; }
    __syncthreads();
    float mu = (ps[0] + ps[1] + ps[2] + ps[3]) * (1.0f / 1024.0f);
    float var = (ps2[0] + ps2[1] + ps2[2] + ps2[3]) * (1.0f / 1024.0f) - mu * mu;
    float rs = rsqrtf(var + 1e-5f);
    int c = threadIdx.x * 4;
    union { unsigned short u[4]; unsigned long long ll; } o;
    #pragma unroll
    for (int j = 0; j < 4; j++) o.u[j] = f2bf((v.a[j] - mu) * rs * g[c + j] + be[c + j]);
    *(unsigned long long*)(out + (size_t)row * 1024 + c) = o.ll;
}

// ---------------- GEMM 128x128, BK=64, XOR-swizzled LDS, XCD-swizzled grid ----------------
// EP 0: out bf16. EP 1: outf = acc + bias[n] + res[m,n] (fp32). EP 2: outb = relu(acc+bias) bf16.
template<int EP>
__global__ __launch_bounds__(256) void gemm_bt(
    const unsigned short* __restrict__ A, const unsigned short* __restrict__ Bw,
    int N, int K,
    const float* __restrict__ bias, const float* __restrict__ res,
    float* __restrict__ outf, unsigned short* __restrict__ outb)
{
    __shared__ __align__(16) unsigned short As[128 * 64];
    __shared__ __align__(16) unsigned short Bs[128 * 64];
    int tid = threadIdx.x, lane = tid & 63, wave = tid >> 6;
    // T1: XCD-aware bijective swizzle (nwg % 8 == 0 for all launch configs here)
    int gx = gridDim.x;
    int nwg = gx * gridDim.y;
    int id = blockIdx.y * gx + blockIdx.x;
    int swz = (id & 7) * (nwg >> 3) + (id >> 3);
    int brow = (swz / gx) * 128, bcol = (swz % gx) * 128;
    int wr = wave >> 1, wc = wave & 1;
    int r = lane & 15, g4 = lane >> 4;
    f32x4 acc[4][4];
    #pragma unroll
    for (int i = 0; i < 4; i++)
        #pragma unroll
        for (int j = 0; j < 4; j++) acc[i][j] = (f32x4){0.f, 0.f, 0.f, 0.f};

    for (int k0 = 0; k0 < K; k0 += 64) {
        __syncthreads();
        #pragma unroll
        for (int q = 0; q < 4; q++) {
            int idx = q * 256 + tid;                 // 0..1023: row = idx>>3, chunk = idx&7
            int row = idx >> 3, gs = (idx & 7) ^ (row & 7);
            gload16(A  + (size_t)(brow + row) * K + k0 + gs * 8, As + idx * 8);
            gload16(Bw + (size_t)(bcol + row) * K + k0 + gs * 8, Bs + idx * 8);
        }
        __syncthreads();
        #pragma unroll
        for (int kk = 0; kk < 2; kk++) {
            bf16x8 af[4], bfr[4];
            #pragma unroll
            for (int mi = 0; mi < 4; mi++) {
                int rh = wr * 64 + mi * 16 + r;
                af[mi] = *(const bf16x8*)&As[rh * 64 + (((kk * 4 + g4) ^ (rh & 7)) << 3)];
            }
            #pragma unroll
            for (int ni = 0; ni < 4; ni++) {
                int rh = wc * 64 + ni * 16 + r;
                bfr[ni] = *(const bf16x8*)&Bs[rh * 64 + (((kk * 4 + g4) ^ (rh & 7)) << 3)];
            }
            #pragma unroll
            for (int mi = 0; mi < 4; mi++)
                #pragma unroll
                for (int ni = 0; ni < 4; ni++)
                    acc[mi][ni] = __builtin_amdgcn_mfma_f32_16x16x32_bf16(af[mi], bfr[ni], acc[mi][ni], 0, 0, 0);
        }
    }

    #pragma unroll
    for (int mi = 0; mi < 4; mi++)
        #pragma unroll
        for (int ni = 0; ni < 4; ni++)
            #pragma unroll
            for (int i = 0; i < 4; i++) {
                int row = brow + wr * 64 + mi * 16 + g4 * 4 + i;
                int col = bcol + wc * 64 + ni * 16 + r;
                float v = acc[mi][ni][i];
                if (EP == 0) {
                    outb[(size_t)row * N + col] = f2bf(v);
                } else if (EP == 1) {
                    outf[(size_t)row * N + col] = v + bias[col] + res[(size_t)row * N + col];
                } else {
                    outb[(size_t)row * N + col] = f2bf(fmaxf(v + bias[col], 0.f));
                }
            }
}

// ---------------- Flash attention (causal), paired q-tiles, double-buffered staging ----------------
__global__ __launch_bounds__(256) void attn_kernel(
    const unsigned short* __restrict__ qkv, unsigned short* __restrict__ att)
{
    __shared__ __align__(16) unsigned short Ks[2][64 * 64];
    __shared__ __align__(16) unsigned short Vt[2][64 * 64];
    __shared__ __align__(16) unsigned short Ps[64 * 64];
    int tid = threadIdx.x, lane = tid & 63, wave = tid >> 6;
    int pi = blockIdx.x;
    int bh = blockIdx.y, bb = bh >> 4, hh = bh & 15;
    int r = lane & 15, g4 = lane >> 4;
    const unsigned short* base = qkv + (size_t)bb * 1024 * 3072;
    const float SCL = 0.03125f * 1.4426950408889634f;   // (1/32) * log2(e)
    int vd = tid & 63, vsb = tid >> 6;                  // V-transpose lane mapping

    #pragma unroll
    for (int sub = 0; sub < 2; sub++) {
        int qi = sub ? (15 - pi) : pi;
        int q0 = qi * 64;

        bf16x8 qf[2];
        int qrow = q0 + wave * 16 + r;
        #pragma unroll
        for (int kk = 0; kk < 2; kk++)
            qf[kk] = *(const bf16x8*)&base[(size_t)qrow * 3072 + hh * 64 + kk * 32 + g4 * 8];

        f32x4 oacc[4];
        #pragma unroll
        for (int i = 0; i < 4; i++) oacc[i] = (f32x4){0.f, 0.f, 0.f, 0.f};
        float m_i[4] = {-INFINITY, -INFINITY, -INFINITY, -INFINITY};
        float l_i[4] = {0.f, 0.f, 0.f, 0.f};

        unsigned short vtmp[16];
        // ---- prologue: stage tile 0 into buffer 0 ----
        {
            #pragma unroll
            for (int half = 0; half < 2; half++) {
                int idx = half * 256 + tid;
                int row = idx >> 3, slot = idx & 7;
                int gs = slot ^ (row & 7);
                gload16(base + (size_t)row * 3072 + 1024 + hh * 64 + gs * 8, &Ks[0][idx * 8]);
            }
            #pragma unroll
            for (int i2 = 0; i2 < 16; i2++)
                vtmp[i2] = base[(size_t)(vsb * 16 + i2) * 3072 + 2048 + hh * 64 + vd];
            union { unsigned short u[8]; bf16x8 v; } w0, w1;
            #pragma unroll
            for (int i2 = 0; i2 < 8; i2++) { w0.u[i2] = vtmp[i2]; w1.u[i2] = vtmp[8 + i2]; }
            int s0 = (vsb * 2) ^ (vd & 7), s1 = (vsb * 2 + 1) ^ (vd & 7);
            *(bf16x8*)&Vt[0][vd * 64 + s0 * 8] = w0.v;
            *(bf16x8*)&Vt[0][vd * 64 + s1 * 8] = w1.v;
        }
        __syncthreads();

        for (int ki = 0; ki <= qi; ki++) {
            int cur = ki & 1;
            bool pre = (ki < qi);
            // ---- issue next tile's staging (async K -> LDS, V -> regs) ----
            if (pre) {
                int k1 = (ki + 1) * 64;
                #pragma unroll
                for (int half = 0; half < 2; half++) {
                    int idx = half * 256 + tid;
                    int row = idx >> 3, slot = idx & 7;
                    int gs = slot ^ (row & 7);
                    gload16(base + (size_t)(k1 + row) * 3072 + 1024 + hh * 64 + gs * 8, &Ks[cur ^ 1][idx * 8]);
                }
                #pragma unroll
                for (int i2 = 0; i2 < 16; i2++)
                    vtmp[i2] = base[(size_t)(k1 + vsb * 16 + i2) * 3072 + 2048 + hh * 64 + vd];
            }

            int k0 = ki * 64;
            // ---- S = Q K^T ----
            f32x4 sacc[4];
            #pragma unroll
            for (int c4 = 0; c4 < 4; c4++) sacc[c4] = (f32x4){0.f, 0.f, 0.f, 0.f};
            #pragma unroll
            for (int c4 = 0; c4 < 4; c4++) {
                int krow = c4 * 16 + r;
                #pragma unroll
                for (int kk = 0; kk < 2; kk++) {
                    int slot = (g4 + kk * 4) ^ (krow & 7);
                    bf16x8 kf = *(const bf16x8*)&Ks[cur][krow * 64 + slot * 8];
                    sacc[c4] = __builtin_amdgcn_mfma_f32_16x16x32_bf16(qf[kk], kf, sacc[c4], 0, 0, 0);
                }
            }
            float pv[4][4];
            bool diag = (ki == qi);
            #pragma unroll
            for (int c4 = 0; c4 < 4; c4++)
                #pragma unroll
                for (int i = 0; i < 4; i++) {
                    float sv = sacc[c4][i] * SCL;
                    if (diag && (k0 + c4 * 16 + r) > (q0 + wave * 16 + g4 * 4 + i)) sv = -INFINITY;
                    pv[c4][i] = sv;
                }
            // ---- online softmax (rows across 16-lane groups) ----
            #pragma unroll
            for (int i = 0; i < 4; i++) {
                float tm = fmaxf(fmaxf(pv[0][i], pv[1][i]), fmaxf(pv[2][i], pv[3][i]));
                tm = fmaxf(tm, __shfl_xor(tm, 1));
                tm = fmaxf(tm, __shfl_xor(tm, 2));
                tm = fmaxf(tm, __shfl_xor(tm, 4));
                tm = fmaxf(tm, __shfl_xor(tm, 8));
                float mn = fmaxf(m_i[i], tm);
                float fs = exp2f(m_i[i] - mn);
                m_i[i] = mn;
                float rowsum = 0.f;
                #pragma unroll
                for (int c4 = 0; c4 < 4; c4++) {
                    float p = exp2f(pv[c4][i] - mn);
                    pv[c4][i] = p;
                    rowsum += p;
                }
                rowsum += __shfl_xor(rowsum, 1);
                rowsum += __shfl_xor(rowsum, 2);
                rowsum += __shfl_xor(rowsum, 4);
                rowsum += __shfl_xor(rowsum, 8);
                l_i[i] = l_i[i] * fs + rowsum;
                #pragma unroll
                for (int n4 = 0; n4 < 4; n4++) oacc[n4][i] *= fs;
                int tl = wave * 16 + g4 * 4 + i;
                #pragma unroll
                for (int c4 = 0; c4 < 4; c4++) {
                    int s = c4 * 16 + r;
                    Ps[tl * 64 + (((s >> 3) ^ (tl & 7)) << 3) + (s & 7)] = f2bf(pv[c4][i]);
                }
            }
            // ---- write next V tile to other buffer (loads have had QK+softmax to land) ----
            if (pre) {
                union { unsigned short u[8]; bf16x8 v; } w0, w1;
                #pragma unroll
                for (int i2 = 0; i2 < 8; i2++) { w0.u[i2] = vtmp[i2]; w1.u[i2] = vtmp[8 + i2]; }
                int s0 = (vsb * 2) ^ (vd & 7), s1 = (vsb * 2 + 1) ^ (vd & 7);
                *(bf16x8*)&Vt[cur ^ 1][vd * 64 + s0 * 8] = w0.v;
                *(bf16x8*)&Vt[cur ^ 1][vd * 64 + s1 * 8] = w1.v;
            }
            // ---- O += P * V ----
            #pragma unroll
            for (int ks = 0; ks < 2; ks++) {
                int tl2 = wave * 16 + r;
                int sb8 = ks * 4 + g4;
                bf16x8 pa = *(const bf16x8*)&Ps[tl2 * 64 + ((sb8 ^ (tl2 & 7)) << 3)];
                #pragma unroll
                for (int n4 = 0; n4 < 4; n4++) {
                    int d = n4 * 16 + r;
                    bf16x8 vf = *(const bf16x8*)&Vt[cur][d * 64 + (((ks * 4 + g4) ^ (d & 7)) << 3)];
                    oacc[n4] = __builtin_amdgcn_mfma_f32_16x16x32_bf16(pa, vf, oacc[n4], 0, 0, 0);
                }
            }
            __syncthreads();   // drains vmcnt (K gload) + lgkm (V ds_writes); buffers consistent
        }

        #pragma unroll
        for (int i = 0; i < 4; i++) {
            float inv = 1.f / l_i[i];
            int trow = q0 + wave * 16 + g4 * 4 + i;
            #pragma unroll
            for (int n4 = 0; n4 < 4; n4++)
                att[((size_t)(bb * 1024 + trow)) * 1024 + hh * 64 + n4 * 16 + r] = f2bf(oacc[n4][i] * inv);
        }
    }
}

// ---------------- host ----------------
extern "C" void kernel_launch(void* const* d_in, const int* in_sizes, int n_in,
                              void* d_out, int out_size, void* d_ws, size_t ws_size,
                              hipStream_t stream)
{
    const float* x     = (const float*)d_in[0];
    const float* Wq    = (const float*)d_in[1];
    const float* Wk    = (const float*)d_in[2];
    const float* Wv    = (const float*)d_in[3];
    const float* eq    = (const float*)d_in[4];
    const float* bq    = (const float*)d_in[5];
    const float* ek    = (const float*)d_in[6];
    const float* bk    = (const float*)d_in[7];
    const float* ev    = (const float*)d_in[8];
    const float* bv    = (const float*)d_in[9];
    const float* Wp    = (const float*)d_in[10];
    const float* ep    = (const float*)d_in[11];
    const float* bp    = (const float*)d_in[12];
    const float* biasp = (const float*)d_in[13];
    const float* W1    = (const float*)d_in[14];
    const float* e1    = (const float*)d_in[15];
    const float* b1    = (const float*)d_in[16];
    const float* bias1 = (const float*)d_in[17];
    const float* W2    = (const float*)d_in[18];
    const float* e2    = (const float*)d_in[19];
    const float* b2    = (const float*)d_in[20];
    const float* bias2 = (const float*)d_in[21];
    const float* g1    = (const float*)d_in[22];
    const float* be1   = (const float*)d_in[23];
    const float* g2    = (const float*)d_in[24];
    const float* be2   = (const float*)d_in[25];

    const size_t MB = 1ull << 20;
    char* ws = (char*)d_ws;
    unsigned short* Wqkvq = (unsigned short*)(ws);            //  6 MB
    unsigned short* Wpq   = (unsigned short*)(ws + 6 * MB);   //  2 MB
    unsigned short* W1q   = (unsigned short*)(ws + 8 * MB);   //  8 MB
    unsigned short* W2q   = (unsigned short*)(ws + 16 * MB);  //  8 MB
    unsigned short* hbuf  = (unsigned short*)(ws + 24 * MB);  // 16 MB
    unsigned short* qkvb  = (unsigned short*)(ws + 40 * MB);  // 48 MB; later f (64 MB)
    unsigned short* fbuf  = qkvb;
    unsigned short* attb  = (unsigned short*)(ws + 88 * MB);  // 16 MB
    float*          x2    = (float*)(ws + 104 * MB);          // 32 MB

    // all 6 weight fake-quants in one dispatch
    quant6_kernel<<<2048, 256, 0, stream>>>(Wq, Wk, Wv, Wp, W1, W2,
                                            eq, ek, ev, ep, e1, e2,
                                            bq, bk, bv, bp, b1, b2,
                                            Wqkvq, Wpq, W1q, W2q);

    ln_kernel<<<8192, 256, 0, stream>>>(x, g1, be1, hbuf);
    // QKV: [8192,3072] bf16
    gemm_bt<0><<<dim3(24, 64), 256, 0, stream>>>(hbuf, Wqkvq, 3072, 1024, nullptr, nullptr, nullptr, qkvb);
    // attention (paired q-tiles, double-buffered)
    attn_kernel<<<dim3(8, 128), 256, 0, stream>>>(qkvb, attb);
    // proj + bias + residual -> x2 (fp32)
    gemm_bt<1><<<dim3(8, 64), 256, 0, stream>>>(attb, Wpq, 1024, 1024, biasp, x, x2, nullptr);
    ln_kernel<<<8192, 256, 0, stream>>>(x2, g2, be2, hbuf);
    // FFN1: relu(h2 W1^T + b1) -> f (bf16)
    gemm_bt<2><<<dim3(32, 64), 256, 0, stream>>>(hbuf, W1q, 4096, 1024, bias1, nullptr, nullptr, fbuf);
    // FFN2: f W2^T + b2 + x2 -> out (fp32)
    gemm_bt<1><<<dim3(8, 64), 256, 0, stream>>>(fbuf, W2q, 1024, 4096, bias2, x2, (float*)d_out, nullptr);
}

// Round 5
// 356.688 us; speedup vs baseline: 1.4092x; 1.1260x over previous
//
#include <hip/hip_runtime.h>
#include <hip/hip_bf16.h>
#include <math.h>

#define DEVI __device__ __forceinline__

typedef __attribute__((ext_vector_type(8))) short bf16x8;
typedef __attribute__((ext_vector_type(4))) float f32x4;

DEVI unsigned short f2bf(float f) {
    union { float f; unsigned u; } v; v.f = f;
    unsigned r = v.u + 0x7FFFu + ((v.u >> 16) & 1u);
    return (unsigned short)(r >> 16);
}

DEVI void gload16(const void* g, void* l) {
    __builtin_amdgcn_global_load_lds((const __attribute__((address_space(1))) void*)g,
                                     (__attribute__((address_space(3))) void*)l, 16, 0, 0);
}

#define WAITVM8() asm volatile("s_waitcnt vmcnt(8)" ::: "memory")
#define WAITVM0() asm volatile("s_waitcnt vmcnt(0)" ::: "memory")
#define WAITLG0() asm volatile("s_waitcnt lgkmcnt(0)" ::: "memory")

// ---------------- fused weight fake-quant (all 6 weights, one dispatch) ----------------
__global__ __launch_bounds__(256) void quant6_kernel(
    const float* __restrict__ Wq, const float* __restrict__ Wk, const float* __restrict__ Wv,
    const float* __restrict__ Wp, const float* __restrict__ W1, const float* __restrict__ W2,
    const float* __restrict__ eq, const float* __restrict__ ek, const float* __restrict__ ev,
    const float* __restrict__ ep, const float* __restrict__ e1, const float* __restrict__ e2,
    const float* __restrict__ bq, const float* __restrict__ bk, const float* __restrict__ bv,
    const float* __restrict__ bp, const float* __restrict__ b1, const float* __restrict__ b2,
    unsigned short* __restrict__ Wqkvq, unsigned short* __restrict__ Wpq,
    unsigned short* __restrict__ W1q, unsigned short* __restrict__ W2q)
{
    const int M1 = 1 << 20;
    const int NCH = 3 * M1;  // 12M elems / 4 per chunk
    for (int c = blockIdx.x * blockDim.x + threadIdx.x; c < NCH; c += gridDim.x * blockDim.x) {
        int elem = c * 4;
        const float *W, *e, *b; unsigned short* o; int lgK, local;
        if (elem < M1)            { W = Wq; e = eq; b = bq; o = Wqkvq;          lgK = 10; local = elem; }
        else if (elem < 2 * M1)   { W = Wk; e = ek; b = bk; o = Wqkvq + M1;     lgK = 10; local = elem - M1; }
        else if (elem < 3 * M1)   { W = Wv; e = ev; b = bv; o = Wqkvq + 2 * M1; lgK = 10; local = elem - 2 * M1; }
        else if (elem < 4 * M1)   { W = Wp; e = ep; b = bp; o = Wpq;            lgK = 10; local = elem - 3 * M1; }
        else if (elem < 8 * M1)   { W = W1; e = e1; b = b1; o = W1q;            lgK = 10; local = elem - 4 * M1; }
        else                      { W = W2; e = e2; b = b2; o = W2q;            lgK = 12; local = elem - 8 * M1; }
        int row = local >> lgK;
        float evv = e[row], bvv = b[row];
        float br = fmaxf(bvv, 0.f);
        float mn, mx;
        if (br > 0.f) { float p = exp2f(br - 1.f); mn = -p; mx = p - 1.f; }
        else          { mn = 0.f; mx = 0.f; }
        float si = exp2f(-evv), so = exp2f(evv);
        union { float4 v4; float a[4]; } v;
        v.v4 = *(const float4*)(W + local);
        union { unsigned short u[4]; unsigned long long ll; } ot;
        #pragma unroll
        for (int j = 0; j < 4; j++) {
            float qw = fminf(fmaxf(si * v.a[j], mn), mx);
            ot.u[j] = f2bf(so * rintf(qw));
        }
        *(unsigned long long*)(o + local) = ot.ll;
    }
}

// ---------------- LayerNorm: fp32 in -> bf16 out ----------------
__global__ __launch_bounds__(256) void ln_kernel(
    const float* __restrict__ x, const float* __restrict__ g, const float* __restrict__ be,
    unsigned short* __restrict__ out)
{
    int row = blockIdx.x;
    union { float4 v4; float a[4]; } v;
    v.v4 = ((const float4*)(x + (size_t)row * 1024))[threadIdx.x];
    float s = v.a[0] + v.a[1] + v.a[2] + v.a[3];
    float s2 = v.a[0]*v.a[0] + v.a[1]*v.a[1] + v.a[2]*v.a[2] + v.a[3]*v.a[3];
    #pragma unroll
    for (int off = 32; off > 0; off >>= 1) { s += __shfl_down(s, off); s2 += __shfl_down(s2, off); }
    __shared__ float ps[4], ps2[4];
    int wave = threadIdx.x >> 6, lane = threadIdx.x & 63;
    if (lane == 0) { ps[wave] = s; ps2[wave] = s2; }
    __syncthreads();
    float mu = (ps[0] + ps[1] + ps[2] + ps[3]) * (1.0f / 1024.0f);
    float var = (ps2[0] + ps2[1] + ps2[2] + ps2[3]) * (1.0f / 1024.0f) - mu * mu;
    float rs = rsqrtf(var + 1e-5f);
    int c = threadIdx.x * 4;
    union { unsigned short u[4]; unsigned long long ll; } o;
    #pragma unroll
    for (int j = 0; j < 4; j++) o.u[j] = f2bf((v.a[j] - mu) * rs * g[c + j] + be[c + j]);
    *(unsigned long long*)(out + (size_t)row * 1024 + c) = o.ll;
}

// ---------------- GEMM 128x128, BK=64, double-buffered counted-vmcnt 2-phase ----------------
// Race ledger: iter t stages buf^1 (8 gload16) then vmcnt(8) -> per-wave FIFO means the
// PREVIOUS iteration's 8 loads (current buf) have landed; BAR1 -> landed for all waves.
// All waves' ds_reads of buf complete before their MFMAs (compiler lgkm waits), hence
// before BAR2; next iteration's stage into that buf is after BAR2. Tail drains vmcnt(0).
#define GSTAGE(buf, kt) do { \
    _Pragma("unroll") for (int q_ = 0; q_ < 4; q_++) { \
        int idx_ = q_ * 256 + tid; int row_ = idx_ >> 3; int gs_ = (idx_ & 7) ^ (row_ & 7); \
        gload16(A  + (size_t)(brow + row_) * K + (kt) * 64 + gs_ * 8, &As[buf][idx_ * 8]); \
        gload16(Bw + (size_t)(bcol + row_) * K + (kt) * 64 + gs_ * 8, &Bs[buf][idx_ * 8]); \
    } } while (0)

template<int EP>
__global__ __launch_bounds__(256) void gemm_bt(
    const unsigned short* __restrict__ A, const unsigned short* __restrict__ Bw,
    int N, int K,
    const float* __restrict__ bias, const float* __restrict__ res,
    float* __restrict__ outf, unsigned short* __restrict__ outb)
{
    __shared__ __align__(16) unsigned short As[2][128 * 64];
    __shared__ __align__(16) unsigned short Bs[2][128 * 64];
    int tid = threadIdx.x, lane = tid & 63, wave = tid >> 6;
    // T1: XCD-aware bijective swizzle (nwg % 8 == 0 for all launch configs here)
    int gx = gridDim.x;
    int nwg = gx * gridDim.y;
    int id = blockIdx.y * gx + blockIdx.x;
    int swz = (id & 7) * (nwg >> 3) + (id >> 3);
    int brow = (swz / gx) * 128, bcol = (swz % gx) * 128;
    int wr = wave >> 1, wc = wave & 1;
    int r = lane & 15, g4 = lane >> 4;
    f32x4 acc[4][4];
    #pragma unroll
    for (int i = 0; i < 4; i++)
        #pragma unroll
        for (int j = 0; j < 4; j++) acc[i][j] = (f32x4){0.f, 0.f, 0.f, 0.f};

    int nt = K >> 6;
    GSTAGE(0, 0);
    __syncthreads();
    int cur = 0;
    for (int t = 0; t < nt; ++t) {
        if (t + 1 < nt) { GSTAGE(cur ^ 1, t + 1); WAITVM8(); }
        else            { WAITVM0(); }
        __builtin_amdgcn_s_barrier();
        #pragma unroll
        for (int kk = 0; kk < 2; kk++) {
            bf16x8 af[4], bfr[4];
            #pragma unroll
            for (int mi = 0; mi < 4; mi++) {
                int rh = wr * 64 + mi * 16 + r;
                af[mi] = *(const bf16x8*)&As[cur][rh * 64 + (((kk * 4 + g4) ^ (rh & 7)) << 3)];
            }
            #pragma unroll
            for (int ni = 0; ni < 4; ni++) {
                int rh = wc * 64 + ni * 16 + r;
                bfr[ni] = *(const bf16x8*)&Bs[cur][rh * 64 + (((kk * 4 + g4) ^ (rh & 7)) << 3)];
            }
            #pragma unroll
            for (int mi = 0; mi < 4; mi++)
                #pragma unroll
                for (int ni = 0; ni < 4; ni++)
                    acc[mi][ni] = __builtin_amdgcn_mfma_f32_16x16x32_bf16(af[mi], bfr[ni], acc[mi][ni], 0, 0, 0);
        }
        __builtin_amdgcn_s_barrier();
        cur ^= 1;
    }

    #pragma unroll
    for (int mi = 0; mi < 4; mi++)
        #pragma unroll
        for (int ni = 0; ni < 4; ni++)
            #pragma unroll
            for (int i = 0; i < 4; i++) {
                int row = brow + wr * 64 + mi * 16 + g4 * 4 + i;
                int col = bcol + wc * 64 + ni * 16 + r;
                float v = acc[mi][ni][i];
                if (EP == 0) {
                    outb[(size_t)row * N + col] = f2bf(v);
                } else if (EP == 1) {
                    outf[(size_t)row * N + col] = v + bias[col] + res[(size_t)row * N + col];
                } else {
                    outb[(size_t)row * N + col] = f2bf(fmaxf(v + bias[col], 0.f));
                }
            }
}

// ---------------- Flash attention (causal), swapped-QK^T in-lane softmax ----------------
// S^T = mfma(K,Q): each lane owns one q-row's 16 k-values per tile -> in-lane reduce +
// 2 shfl_xor; P written as packed b64 to wave-private swizzled Ps; PV = mfma(V^T, P^T).
__global__ __launch_bounds__(256) void attn_kernel(
    const unsigned short* __restrict__ qkv, unsigned short* __restrict__ att)
{
    __shared__ __align__(16) unsigned short Ks[2][64 * 64];
    __shared__ __align__(16) unsigned short Vt[2][64 * 64];
    __shared__ __align__(16) unsigned short Ps[64 * 64];
    int tid = threadIdx.x, lane = tid & 63, wave = tid >> 6;
    int pi = blockIdx.x;
    int bh = blockIdx.y, bb = bh >> 4, hh = bh & 15;
    int r = lane & 15, g4 = lane >> 4;
    const unsigned short* base = qkv + (size_t)bb * 1024 * 3072;
    const float SCL = 0.03125f * 1.4426950408889634f;   // (1/32) * log2(e)
    int vd = tid & 63, vsb = tid >> 6;                  // V-transpose lane mapping
    int prow = wave * 16 + r;                            // q-local row this lane owns
    int pswz = (r & 7) << 3;                             // Ps XOR swizzle (ushort-index bits 3-5)

    #pragma unroll
    for (int sub = 0; sub < 2; sub++) {
        int qi = sub ? (15 - pi) : pi;
        int q0 = qi * 64;
        int qrow = q0 + prow;

        bf16x8 qf[2];
        #pragma unroll
        for (int kk = 0; kk < 2; kk++)
            qf[kk] = *(const bf16x8*)&base[(size_t)qrow * 3072 + hh * 64 + kk * 32 + g4 * 8];

        f32x4 oacc[4];
        #pragma unroll
        for (int i = 0; i < 4; i++) oacc[i] = (f32x4){0.f, 0.f, 0.f, 0.f};
        float m_i = -INFINITY, l_i = 0.f;

        unsigned short vtmp[16];
        // ---- prologue: stage tile 0 into buffer 0 ----
        {
            #pragma unroll
            for (int half = 0; half < 2; half++) {
                int idx = half * 256 + tid;
                int row = idx >> 3, slot = idx & 7;
                int gs = slot ^ (row & 7);
                gload16(base + (size_t)row * 3072 + 1024 + hh * 64 + gs * 8, &Ks[0][idx * 8]);
            }
            #pragma unroll
            for (int i2 = 0; i2 < 16; i2++)
                vtmp[i2] = base[(size_t)(vsb * 16 + i2) * 3072 + 2048 + hh * 64 + vd];
            union { unsigned short u[8]; bf16x8 v; } w0, w1;
            #pragma unroll
            for (int i2 = 0; i2 < 8; i2++) { w0.u[i2] = vtmp[i2]; w1.u[i2] = vtmp[8 + i2]; }
            int s0 = (vsb * 2) ^ (vd & 7), s1 = (vsb * 2 + 1) ^ (vd & 7);
            *(bf16x8*)&Vt[0][vd * 64 + s0 * 8] = w0.v;
            *(bf16x8*)&Vt[0][vd * 64 + s1 * 8] = w1.v;
        }
        __syncthreads();

        for (int ki = 0; ki <= qi; ki++) {
            int cur = ki & 1;
            bool pre = (ki < qi);
            // ---- issue next tile's staging (async K -> LDS, V -> regs) ----
            if (pre) {
                int k1 = (ki + 1) * 64;
                #pragma unroll
                for (int half = 0; half < 2; half++) {
                    int idx = half * 256 + tid;
                    int row = idx >> 3, slot = idx & 7;
                    int gs = slot ^ (row & 7);
                    gload16(base + (size_t)(k1 + row) * 3072 + 1024 + hh * 64 + gs * 8, &Ks[cur ^ 1][idx * 8]);
                }
                #pragma unroll
                for (int i2 = 0; i2 < 16; i2++)
                    vtmp[i2] = base[(size_t)(k1 + vsb * 16 + i2) * 3072 + 2048 + hh * 64 + vd];
            }

            int k0 = ki * 64;
            // ---- S^T = K Q^T : lane holds S[k = k0+c4*16+g4*4+i][q = qrow] ----
            f32x4 sacc[4];
            #pragma unroll
            for (int c4 = 0; c4 < 4; c4++) sacc[c4] = (f32x4){0.f, 0.f, 0.f, 0.f};
            #pragma unroll
            for (int c4 = 0; c4 < 4; c4++) {
                int krow = c4 * 16 + r;
                #pragma unroll
                for (int kk = 0; kk < 2; kk++) {
                    int slot = (g4 + kk * 4) ^ (krow & 7);
                    bf16x8 kf = *(const bf16x8*)&Ks[cur][krow * 64 + slot * 8];
                    sacc[c4] = __builtin_amdgcn_mfma_f32_16x16x32_bf16(kf, qf[kk], sacc[c4], 0, 0, 0);
                }
            }
            // ---- mask + in-lane max ----
            bool diag = (ki == qi);
            float sv[4][4];
            float smax = -INFINITY;
            #pragma unroll
            for (int c4 = 0; c4 < 4; c4++)
                #pragma unroll
                for (int i = 0; i < 4; i++) {
                    float s = sacc[c4][i];
                    if (diag && (k0 + c4 * 16 + g4 * 4 + i) > qrow) s = -INFINITY;
                    sv[c4][i] = s;
                    smax = fmaxf(smax, s);
                }
            smax = fmaxf(smax, __shfl_xor(smax, 16));
            smax = fmaxf(smax, __shfl_xor(smax, 32));
            float mn = fmaxf(m_i, smax);
            float fs = exp2f((m_i - mn) * SCL);
            float nb = -mn * SCL;
            m_i = mn;
            float rsum = 0.f;
            float pv[4][4];
            #pragma unroll
            for (int c4 = 0; c4 < 4; c4++)
                #pragma unroll
                for (int i = 0; i < 4; i++) {
                    float p = exp2f(fmaf(sv[c4][i], SCL, nb));
                    pv[c4][i] = p;
                    rsum += p;
                }
            rsum += __shfl_xor(rsum, 16);
            rsum += __shfl_xor(rsum, 32);
            l_i = l_i * fs + rsum;
            #pragma unroll
            for (int n4 = 0; n4 < 4; n4++)
                #pragma unroll
                for (int i = 0; i < 4; i++) oacc[n4][i] *= fs;
            // ---- pack P -> Ps (wave-private rows, b64 writes, XOR-swizzled) ----
            #pragma unroll
            for (int c4 = 0; c4 < 4; c4++) {
                union { unsigned short u[4]; unsigned long long ll; } pk;
                #pragma unroll
                for (int i = 0; i < 4; i++) pk.u[i] = f2bf(pv[c4][i]);
                int idx16 = (prow * 64 + c4 * 16 + g4 * 4) ^ pswz;
                *(unsigned long long*)&Ps[idx16] = pk.ll;
            }
            WAITLG0();   // order same-wave Ps writes before Ps reads below
            // ---- write next V tile to other buffer ----
            if (pre) {
                union { unsigned short u[8]; bf16x8 v; } w0, w1;
                #pragma unroll
                for (int i2 = 0; i2 < 8; i2++) { w0.u[i2] = vtmp[i2]; w1.u[i2] = vtmp[8 + i2]; }
                int s0 = (vsb * 2) ^ (vd & 7), s1 = (vsb * 2 + 1) ^ (vd & 7);
                *(bf16x8*)&Vt[cur ^ 1][vd * 64 + s0 * 8] = w0.v;
                *(bf16x8*)&Vt[cur ^ 1][vd * 64 + s1 * 8] = w1.v;
            }
            // ---- O^T += V^T P^T ----
            bf16x8 pa[2];
            #pragma unroll
            for (int kk = 0; kk < 2; kk++)
                pa[kk] = *(const bf16x8*)&Ps[(prow * 64 + kk * 32 + g4 * 8) ^ pswz];
            #pragma unroll
            for (int n4 = 0; n4 < 4; n4++) {
                int d = n4 * 16 + r;
                #pragma unroll
                for (int kk = 0; kk < 2; kk++) {
                    bf16x8 vf = *(const bf16x8*)&Vt[cur][d * 64 + (((kk * 4 + g4) ^ (d & 7)) << 3)];
                    oacc[n4] = __builtin_amdgcn_mfma_f32_16x16x32_bf16(vf, pa[kk], oacc[n4], 0, 0, 0);
                }
            }
            __syncthreads();   // drains vmcnt (K gload) + lgkm (V ds_writes); buffers consistent
        }

        // ---- write O: lane owns q-row qrow; d = n4*16 + g4*4 + i (packed b64) ----
        float inv = 1.f / l_i;
        #pragma unroll
        for (int n4 = 0; n4 < 4; n4++) {
            union { unsigned short u[4]; unsigned long long ll; } ok;
            #pragma unroll
            for (int i = 0; i < 4; i++) ok.u[i] = f2bf(oacc[n4][i] * inv);
            size_t oidx = ((size_t)(bb * 1024 + qrow)) * 1024 + hh * 64 + n4 * 16 + g4 * 4;
            *(unsigned long long*)&att[oidx] = ok.ll;
        }
    }
}

// ---------------- host ----------------
extern "C" void kernel_launch(void* const* d_in, const int* in_sizes, int n_in,
                              void* d_out, int out_size, void* d_ws, size_t ws_size,
                              hipStream_t stream)
{
    const float* x     = (const float*)d_in[0];
    const float* Wq    = (const float*)d_in[1];
    const float* Wk    = (const float*)d_in[2];
    const float* Wv    = (const float*)d_in[3];
    const float* eq    = (const float*)d_in[4];
    const float* bq    = (const float*)d_in[5];
    const float* ek    = (const float*)d_in[6];
    const float* bk    = (const float*)d_in[7];
    const float* ev    = (const float*)d_in[8];
    const float* bv    = (const float*)d_in[9];
    const float* Wp    = (const float*)d_in[10];
    const float* ep    = (const float*)d_in[11];
    const float* bp    = (const float*)d_in[12];
    const float* biasp = (const float*)d_in[13];
    const float* W1    = (const float*)d_in[14];
    const float* e1    = (const float*)d_in[15];
    const float* b1    = (const float*)d_in[16];
    const float* bias1 = (const float*)d_in[17];
    const float* W2    = (const float*)d_in[18];
    const float* e2    = (const float*)d_in[19];
    const float* b2    = (const float*)d_in[20];
    const float* bias2 = (const float*)d_in[21];
    const float* g1    = (const float*)d_in[22];
    const float* be1   = (const float*)d_in[23];
    const float* g2    = (const float*)d_in[24];
    const float* be2   = (const float*)d_in[25];

    const size_t MB = 1ull << 20;
    char* ws = (char*)d_ws;
    unsigned short* Wqkvq = (unsigned short*)(ws);            //  6 MB
    unsigned short* Wpq   = (unsigned short*)(ws + 6 * MB);   //  2 MB
    unsigned short* W1q   = (unsigned short*)(ws + 8 * MB);   //  8 MB
    unsigned short* W2q   = (unsigned short*)(ws + 16 * MB);  //  8 MB
    unsigned short* hbuf  = (unsigned short*)(ws + 24 * MB);  // 16 MB
    unsigned short* qkvb  = (unsigned short*)(ws + 40 * MB);  // 48 MB; later f (64 MB)
    unsigned short* fbuf  = qkvb;
    unsigned short* attb  = (unsigned short*)(ws + 88 * MB);  // 16 MB
    float*          x2    = (float*)(ws + 104 * MB);          // 32 MB

    quant6_kernel<<<2048, 256, 0, stream>>>(Wq, Wk, Wv, Wp, W1, W2,
                                            eq, ek, ev, ep, e1, e2,
                                            bq, bk, bv, bp, b1, b2,
                                            Wqkvq, Wpq, W1q, W2q);

    ln_kernel<<<8192, 256, 0, stream>>>(x, g1, be1, hbuf);
    // QKV: [8192,3072] bf16
    gemm_bt<0><<<dim3(24, 64), 256, 0, stream>>>(hbuf, Wqkvq, 3072, 1024, nullptr, nullptr, nullptr, qkvb);
    // attention (paired q-tiles, swapped-QK softmax)
    attn_kernel<<<dim3(8, 128), 256, 0, stream>>>(qkvb, attb);
    // proj + bias + residual -> x2 (fp32)
    gemm_bt<1><<<dim3(8, 64), 256, 0, stream>>>(attb, Wpq, 1024, 1024, biasp, x, x2, nullptr);
    ln_kernel<<<8192, 256, 0, stream>>>(x2, g2, be2, hbuf);
    // FFN1: relu(h2 W1^T + b1) -> f (bf16)
    gemm_bt<2><<<dim3(32, 64), 256, 0, stream>>>(hbuf, W1q, 4096, 1024, bias1, nullptr, nullptr, fbuf);
    // FFN2: f W2^T + b2 + x2 -> out (fp32)
    gemm_bt<1><<<dim3(8, 64), 256, 0, stream>>>(fbuf, W2q, 1024, 4096, bias2, x2, (float*)d_out, nullptr);
}

// Round 6
// 349.513 us; speedup vs baseline: 1.4382x; 1.0205x over previous
//
#include <hip/hip_runtime.h>
#include <hip/hip_bf16.h>
#include <math.h>

#define DEVI __device__ __forceinline__

typedef __attribute__((ext_vector_type(8))) short bf16x8;
typedef __attribute__((ext_vector_type(4))) float f32x4;

DEVI unsigned short f2bf(float f) {
    union { float f; unsigned u; } v; v.f = f;
    unsigned r = v.u + 0x7FFFu + ((v.u >> 16) & 1u);
    return (unsigned short)(r >> 16);
}

DEVI void gload16(const void* g, void* l) {
    __builtin_amdgcn_global_load_lds((const __attribute__((address_space(1))) void*)g,
                                     (__attribute__((address_space(3))) void*)l, 16, 0, 0);
}

#define WAITVM8() asm volatile("s_waitcnt vmcnt(8)" ::: "memory")
#define WAITVM4() asm volatile("s_waitcnt vmcnt(4)" ::: "memory")
#define WAITVM0() asm volatile("s_waitcnt vmcnt(0)" ::: "memory")
#define WAITLG0() asm volatile("s_waitcnt lgkmcnt(0)" ::: "memory")
#define WAITLG8() asm volatile("s_waitcnt lgkmcnt(8)" ::: "memory")
#define BAR()     __builtin_amdgcn_s_barrier()
#define SB()      __builtin_amdgcn_sched_barrier(0)

// ---------------- fused weight fake-quant (all 6 weights, one dispatch) ----------------
__global__ __launch_bounds__(256) void quant6_kernel(
    const float* __restrict__ Wq, const float* __restrict__ Wk, const float* __restrict__ Wv,
    const float* __restrict__ Wp, const float* __restrict__ W1, const float* __restrict__ W2,
    const float* __restrict__ eq, const float* __restrict__ ek, const float* __restrict__ ev,
    const float* __restrict__ ep, const float* __restrict__ e1, const float* __restrict__ e2,
    const float* __restrict__ bq, const float* __restrict__ bk, const float* __restrict__ bv,
    const float* __restrict__ bp, const float* __restrict__ b1, const float* __restrict__ b2,
    unsigned short* __restrict__ Wqkvq, unsigned short* __restrict__ Wpq,
    unsigned short* __restrict__ W1q, unsigned short* __restrict__ W2q)
{
    const int M1 = 1 << 20;
    const int NCH = 3 * M1;  // 12M elems / 4 per chunk
    for (int c = blockIdx.x * blockDim.x + threadIdx.x; c < NCH; c += gridDim.x * blockDim.x) {
        int elem = c * 4;
        const float *W, *e, *b; unsigned short* o; int lgK, local;
        if (elem < M1)            { W = Wq; e = eq; b = bq; o = Wqkvq;          lgK = 10; local = elem; }
        else if (elem < 2 * M1)   { W = Wk; e = ek; b = bk; o = Wqkvq + M1;     lgK = 10; local = elem - M1; }
        else if (elem < 3 * M1)   { W = Wv; e = ev; b = bv; o = Wqkvq + 2 * M1; lgK = 10; local = elem - 2 * M1; }
        else if (elem < 4 * M1)   { W = Wp; e = ep; b = bp; o = Wpq;            lgK = 10; local = elem - 3 * M1; }
        else if (elem < 8 * M1)   { W = W1; e = e1; b = b1; o = W1q;            lgK = 10; local = elem - 4 * M1; }
        else                      { W = W2; e = e2; b = b2; o = W2q;            lgK = 12; local = elem - 8 * M1; }
        int row = local >> lgK;
        float evv = e[row], bvv = b[row];
        float br = fmaxf(bvv, 0.f);
        float mn, mx;
        if (br > 0.f) { float p = exp2f(br - 1.f); mn = -p; mx = p - 1.f; }
        else          { mn = 0.f; mx = 0.f; }
        float si = exp2f(-evv), so = exp2f(evv);
        union { float4 v4; float a[4]; } v;
        v.v4 = *(const float4*)(W + local);
        union { unsigned short u[4]; unsigned long long ll; } ot;
        #pragma unroll
        for (int j = 0; j < 4; j++) {
            float qw = fminf(fmaxf(si * v.a[j], mn), mx);
            ot.u[j] = f2bf(so * rintf(qw));
        }
        *(unsigned long long*)(o + local) = ot.ll;
    }
}

// ---------------- LayerNorm: fp32 in -> bf16 out ----------------
__global__ __launch_bounds__(256) void ln_kernel(
    const float* __restrict__ x, const float* __restrict__ g, const float* __restrict__ be,
    unsigned short* __restrict__ out)
{
    int row = blockIdx.x;
    union { float4 v4; float a[4]; } v;
    v.v4 = ((const float4*)(x + (size_t)row * 1024))[threadIdx.x];
    float s = v.a[0] + v.a[1] + v.a[2] + v.a[3];
    float s2 = v.a[0]*v.a[0] + v.a[1]*v.a[1] + v.a[2]*v.a[2] + v.a[3]*v.a[3];
    #pragma unroll
    for (int off = 32; off > 0; off >>= 1) { s += __shfl_down(s, off); s2 += __shfl_down(s2, off); }
    __shared__ float ps[4], ps2[4];
    int wave = threadIdx.x >> 6, lane = threadIdx.x & 63;
    if (lane == 0) { ps[wave] = s; ps2[wave] = s2; }
    __syncthreads();
    float mu = (ps[0] + ps[1] + ps[2] + ps[3]) * (1.0f / 1024.0f);
    float var = (ps2[0] + ps2[1] + ps2[2] + ps2[3]) * (1.0f / 1024.0f) - mu * mu;
    float rs = rsqrtf(var + 1e-5f);
    int c = threadIdx.x * 4;
    union { unsigned short u[4]; unsigned long long ll; } o;
    #pragma unroll
    for (int j = 0; j < 4; j++) o.u[j] = f2bf((v.a[j] - mu) * rs * g[c + j] + be[c + j]);
    *(unsigned long long*)(out + (size_t)row * 1024 + c) = o.ll;
}

// ---------------- GEMM 128x128, BK=64, double-buffered counted-vmcnt 2-phase ----------------
#define GSTAGE(buf, kt) do { \
    _Pragma("unroll") for (int q_ = 0; q_ < 4; q_++) { \
        int idx_ = q_ * 256 + tid; int row_ = idx_ >> 3; int gs_ = (idx_ & 7) ^ (row_ & 7); \
        gload16(A  + (size_t)(brow + row_) * K + (kt) * 64 + gs_ * 8, &As[buf][idx_ * 8]); \
        gload16(Bw + (size_t)(bcol + row_) * K + (kt) * 64 + gs_ * 8, &Bs[buf][idx_ * 8]); \
    } } while (0)

template<int EP>
__global__ __launch_bounds__(256) void gemm_bt(
    const unsigned short* __restrict__ A, const unsigned short* __restrict__ Bw,
    int N, int K,
    const float* __restrict__ bias, const float* __restrict__ res,
    float* __restrict__ outf, unsigned short* __restrict__ outb)
{
    __shared__ __align__(16) unsigned short As[2][128 * 64];
    __shared__ __align__(16) unsigned short Bs[2][128 * 64];
    int tid = threadIdx.x, lane = tid & 63, wave = tid >> 6;
    int gx = gridDim.x;
    int nwg = gx * gridDim.y;
    int id = blockIdx.y * gx + blockIdx.x;
    int swz = (id & 7) * (nwg >> 3) + (id >> 3);
    int brow = (swz / gx) * 128, bcol = (swz % gx) * 128;
    int wr = wave >> 1, wc = wave & 1;
    int r = lane & 15, g4 = lane >> 4;
    f32x4 acc[4][4];
    #pragma unroll
    for (int i = 0; i < 4; i++)
        #pragma unroll
        for (int j = 0; j < 4; j++) acc[i][j] = (f32x4){0.f, 0.f, 0.f, 0.f};

    int nt = K >> 6;
    GSTAGE(0, 0);
    __syncthreads();
    int cur = 0;
    for (int t = 0; t < nt; ++t) {
        if (t + 1 < nt) { GSTAGE(cur ^ 1, t + 1); WAITVM8(); }
        else            { WAITVM0(); }
        __builtin_amdgcn_s_barrier();
        #pragma unroll
        for (int kk = 0; kk < 2; kk++) {
            bf16x8 af[4], bfr[4];
            #pragma unroll
            for (int mi = 0; mi < 4; mi++) {
                int rh = wr * 64 + mi * 16 + r;
                af[mi] = *(const bf16x8*)&As[cur][rh * 64 + (((kk * 4 + g4) ^ (rh & 7)) << 3)];
            }
            #pragma unroll
            for (int ni = 0; ni < 4; ni++) {
                int rh = wc * 64 + ni * 16 + r;
                bfr[ni] = *(const bf16x8*)&Bs[cur][rh * 64 + (((kk * 4 + g4) ^ (rh & 7)) << 3)];
            }
            #pragma unroll
            for (int mi = 0; mi < 4; mi++)
                #pragma unroll
                for (int ni = 0; ni < 4; ni++)
                    acc[mi][ni] = __builtin_amdgcn_mfma_f32_16x16x32_bf16(af[mi], bfr[ni], acc[mi][ni], 0, 0, 0);
        }
        __builtin_amdgcn_s_barrier();
        cur ^= 1;
    }

    #pragma unroll
    for (int mi = 0; mi < 4; mi++)
        #pragma unroll
        for (int ni = 0; ni < 4; ni++)
            #pragma unroll
            for (int i = 0; i < 4; i++) {
                int row = brow + wr * 64 + mi * 16 + g4 * 4 + i;
                int col = bcol + wc * 64 + ni * 16 + r;
                float v = acc[mi][ni][i];
                if (EP == 0) {
                    outb[(size_t)row * N + col] = f2bf(v);
                } else if (EP == 1) {
                    outf[(size_t)row * N + col] = v + bias[col] + res[(size_t)row * N + col];
                } else {
                    outb[(size_t)row * N + col] = f2bf(fmaxf(v + bias[col], 0.f));
                }
            }
}

// ---------------- GEMM 256x256 8-phase (HK-derived; ledger re-verified) ----------------
// Per-wave vmcnt ledger (steady state, iter t): entering P1 outstanding = {B0(t+1),B1(t+1)} (4).
// P1 +A0(t+1)=6, P2 +A1(t+1)=8, P3 +B0(t+2)=10, P4 +B1(t+2)=12 then vmcnt(4) -> lands all
// of tile t+1 before P5-P8 read buf1. P5..P8 stage tile t+2 A and tile t+3 B; P8 vmcnt(4)
// lands tile t+2 before next-iter P1 reads buf0. Prologue establishes the invariant; tail
// branches drain with vmcnt(0). Every consumer ds_read is covered by {same-wave vmcnt wait
// before a barrier} + {WAITLG0+sched_barrier before MFMA} (rule 18).
#define STAGE_A(b, h, kt) do { \
    _Pragma("unroll") \
    for (int ld = 0; ld < 2; ld++) { \
        int idx = ld * 512 + tid; int rw = idx >> 3; int gs = (idx & 7) ^ (rw & 7); \
        gload16(Aa + (size_t)(brow + (h) * 128 + rw) * K + (kt) * 64 + gs * 8, &As[b][h][idx * 8]); \
    } } while (0)

#define STAGE_B(b, h, kt) do { \
    _Pragma("unroll") \
    for (int ld = 0; ld < 2; ld++) { \
        int idx = ld * 512 + tid; int rw = idx >> 3; int gs = (idx & 7) ^ (rw & 7); \
        gload16(Bw + (size_t)(bcol + (h) * 128 + rw) * K + (kt) * 64 + gs * 8, &Bs[b][h][idx * 8]); \
    } } while (0)

#define RD_A(b, mh) do { \
    _Pragma("unroll") for (int mi = 0; mi < 4; mi++) \
    _Pragma("unroll") for (int kk = 0; kk < 2; kk++) { \
        int rh = (mh) * 64 + mi * 16 + r; \
        af[mi][kk] = *(const bf16x8*)&As[b][wr][rh * 64 + (((kk * 4 + g4) ^ (rh & 7)) << 3)]; \
    } } while (0)

#define RD_B2(b, nh) do { \
    _Pragma("unroll") for (int nj = 0; nj < 2; nj++) \
    _Pragma("unroll") for (int kk = 0; kk < 2; kk++) { \
        int rh = (wc & 1) * 64 + ((nh) * 2 + nj) * 16 + r; \
        bfr[(nh) * 2 + nj][kk] = *(const bf16x8*)&Bs[b][wc >> 1][rh * 64 + (((kk * 4 + g4) ^ (rh & 7)) << 3)]; \
    } } while (0)

#define QUAD(mh, nh) do { \
    __builtin_amdgcn_s_setprio(1); \
    _Pragma("unroll") for (int mi = 0; mi < 4; mi++) \
    _Pragma("unroll") for (int nj = 0; nj < 2; nj++) \
    _Pragma("unroll") for (int kk = 0; kk < 2; kk++) \
        acc[(mh) * 4 + mi][(nh) * 2 + nj] = __builtin_amdgcn_mfma_f32_16x16x32_bf16( \
            af[mi][kk], bfr[(nh) * 2 + nj][kk], acc[(mh) * 4 + mi][(nh) * 2 + nj], 0, 0, 0); \
    __builtin_amdgcn_s_setprio(0); \
    } while (0)

template<int EP>
__global__ __launch_bounds__(512, 2) void gemm256(
    const unsigned short* __restrict__ Aa, const unsigned short* __restrict__ Bw,
    int N, int K,
    const float* __restrict__ bias, const float* __restrict__ res,
    float* __restrict__ outf, unsigned short* __restrict__ outb)
{
    __shared__ __align__(16) unsigned short As[2][2][128 * 64];
    __shared__ __align__(16) unsigned short Bs[2][2][128 * 64];
    int tid = threadIdx.x, lane = tid & 63, wave = tid >> 6;
    int gx = gridDim.x;
    int nwg = gx * gridDim.y;
    int id = blockIdx.y * gx + blockIdx.x;
    int swz = (id & 7) * (nwg >> 3) + (id >> 3);
    int brow = (swz / gx) * 256, bcol = (swz % gx) * 256;
    int wr = wave >> 2, wc = wave & 3;
    int r = lane & 15, g4 = lane >> 4;
    int KT = K >> 6;

    f32x4 acc[8][4];
    #pragma unroll
    for (int i = 0; i < 8; i++)
        #pragma unroll
        for (int j = 0; j < 4; j++) acc[i][j] = (f32x4){0.f, 0.f, 0.f, 0.f};
    bf16x8 af[4][2], bfr[4][2];

    // prologue: tile0 fully, tile1 B halves
    STAGE_A(0, 0, 0); STAGE_A(0, 1, 0); STAGE_B(0, 0, 0); STAGE_B(0, 1, 0);
    STAGE_B(1, 0, 1); STAGE_B(1, 1, 1);
    WAITVM4();
    BAR();

    for (int t = 0; t < KT; t += 2) {
        // P1: tile t (buf0), quad(0,0); stage A0(t+1)
        RD_A(0, 0); RD_B2(0, 0);
        STAGE_A(1, 0, t + 1);
        WAITLG8();
        BAR(); WAITLG0(); SB();
        QUAD(0, 0);
        BAR();
        // P2: quad(0,1); stage A1(t+1)
        RD_B2(0, 1);
        STAGE_A(1, 1, t + 1);
        BAR(); WAITLG0(); SB();
        QUAD(0, 1);
        BAR();
        // P3: quad(1,1); stage B0(t+2)
        RD_A(0, 1);
        if (t + 2 < KT) STAGE_B(0, 0, t + 2);
        BAR(); WAITLG0(); SB();
        QUAD(1, 1);
        BAR();
        // P4: quad(1,0); stage B1(t+2); counted vmcnt
        if (t + 2 < KT) { STAGE_B(0, 1, t + 2); WAITVM4(); } else { WAITVM0(); }
        BAR(); WAITLG0(); SB();
        QUAD(1, 0);
        BAR();
        // P5: tile t+1 (buf1), quad(0,0); stage A0(t+2)
        RD_A(1, 0); RD_B2(1, 0);
        if (t + 2 < KT) STAGE_A(0, 0, t + 2);
        WAITLG8();
        BAR(); WAITLG0(); SB();
        QUAD(0, 0);
        BAR();
        // P6: quad(0,1); stage A1(t+2)
        RD_B2(1, 1);
        if (t + 2 < KT) STAGE_A(0, 1, t + 2);
        BAR(); WAITLG0(); SB();
        QUAD(0, 1);
        BAR();
        // P7: quad(1,1); stage B0(t+3)
        RD_A(1, 1);
        if (t + 3 < KT) STAGE_B(1, 0, t + 3);
        BAR(); WAITLG0(); SB();
        QUAD(1, 1);
        BAR();
        // P8: quad(1,0); stage B1(t+3); counted vmcnt
        if (t + 3 < KT) { STAGE_B(1, 1, t + 3); WAITVM4(); } else { WAITVM0(); }
        BAR(); WAITLG0(); SB();
        QUAD(1, 0);
        BAR();
    }

    #pragma unroll
    for (int m = 0; m < 8; m++)
        #pragma unroll
        for (int n = 0; n < 4; n++)
            #pragma unroll
            for (int j = 0; j < 4; j++) {
                int row = brow + wr * 128 + m * 16 + g4 * 4 + j;
                int col = bcol + wc * 64 + n * 16 + r;
                float v = acc[m][n][j];
                if (EP == 0) {
                    outb[(size_t)row * N + col] = f2bf(v);
                } else if (EP == 1) {
                    outf[(size_t)row * N + col] = v + bias[col] + res[(size_t)row * N + col];
                } else {
                    outb[(size_t)row * N + col] = f2bf(fmaxf(v + bias[col], 0.f));
                }
            }
}

// ---------------- Flash attention (causal), swapped-QK^T in-lane softmax ----------------
__global__ __launch_bounds__(256) void attn_kernel(
    const unsigned short* __restrict__ qkv, unsigned short* __restrict__ att)
{
    __shared__ __align__(16) unsigned short Ks[2][64 * 64];
    __shared__ __align__(16) unsigned short Vt[2][64 * 64];
    __shared__ __align__(16) unsigned short Ps[64 * 64];
    int tid = threadIdx.x, lane = tid & 63, wave = tid >> 6;
    int pi = blockIdx.x;
    int bh = blockIdx.y, bb = bh >> 4, hh = bh & 15;
    int r = lane & 15, g4 = lane >> 4;
    const unsigned short* base = qkv + (size_t)bb * 1024 * 3072;
    const float SCL = 0.03125f * 1.4426950408889634f;   // (1/32) * log2(e)
    int vd = tid & 63, vsb = tid >> 6;
    int prow = wave * 16 + r;
    int pswz = (r & 7) << 3;

    #pragma unroll
    for (int sub = 0; sub < 2; sub++) {
        int qi = sub ? (15 - pi) : pi;
        int q0 = qi * 64;
        int qrow = q0 + prow;

        bf16x8 qf[2];
        #pragma unroll
        for (int kk = 0; kk < 2; kk++)
            qf[kk] = *(const bf16x8*)&base[(size_t)qrow * 3072 + hh * 64 + kk * 32 + g4 * 8];

        f32x4 oacc[4];
        #pragma unroll
        for (int i = 0; i < 4; i++) oacc[i] = (f32x4){0.f, 0.f, 0.f, 0.f};
        float m_i = -INFINITY, l_i = 0.f;

        unsigned short vtmp[16];
        {
            #pragma unroll
            for (int half = 0; half < 2; half++) {
                int idx = half * 256 + tid;
                int row = idx >> 3, slot = idx & 7;
                int gs = slot ^ (row & 7);
                gload16(base + (size_t)row * 3072 + 1024 + hh * 64 + gs * 8, &Ks[0][idx * 8]);
            }
            #pragma unroll
            for (int i2 = 0; i2 < 16; i2++)
                vtmp[i2] = base[(size_t)(vsb * 16 + i2) * 3072 + 2048 + hh * 64 + vd];
            union { unsigned short u[8]; bf16x8 v; } w0, w1;
            #pragma unroll
            for (int i2 = 0; i2 < 8; i2++) { w0.u[i2] = vtmp[i2]; w1.u[i2] = vtmp[8 + i2]; }
            int s0 = (vsb * 2) ^ (vd & 7), s1 = (vsb * 2 + 1) ^ (vd & 7);
            *(bf16x8*)&Vt[0][vd * 64 + s0 * 8] = w0.v;
            *(bf16x8*)&Vt[0][vd * 64 + s1 * 8] = w1.v;
        }
        __syncthreads();

        for (int ki = 0; ki <= qi; ki++) {
            int cur = ki & 1;
            bool pre = (ki < qi);
            if (pre) {
                int k1 = (ki + 1) * 64;
                #pragma unroll
                for (int half = 0; half < 2; half++) {
                    int idx = half * 256 + tid;
                    int row = idx >> 3, slot = idx & 7;
                    int gs = slot ^ (row & 7);
                    gload16(base + (size_t)(k1 + row) * 3072 + 1024 + hh * 64 + gs * 8, &Ks[cur ^ 1][idx * 8]);
                }
                #pragma unroll
                for (int i2 = 0; i2 < 16; i2++)
                    vtmp[i2] = base[(size_t)(k1 + vsb * 16 + i2) * 3072 + 2048 + hh * 64 + vd];
            }

            int k0 = ki * 64;
            f32x4 sacc[4];
            #pragma unroll
            for (int c4 = 0; c4 < 4; c4++) sacc[c4] = (f32x4){0.f, 0.f, 0.f, 0.f};
            #pragma unroll
            for (int c4 = 0; c4 < 4; c4++) {
                int krow = c4 * 16 + r;
                #pragma unroll
                for (int kk = 0; kk < 2; kk++) {
                    int slot = (g4 + kk * 4) ^ (krow & 7);
                    bf16x8 kf = *(const bf16x8*)&Ks[cur][krow * 64 + slot * 8];
                    sacc[c4] = __builtin_amdgcn_mfma_f32_16x16x32_bf16(kf, qf[kk], sacc[c4], 0, 0, 0);
                }
            }
            bool diag = (ki == qi);
            float sv[4][4];
            float smax = -INFINITY;
            #pragma unroll
            for (int c4 = 0; c4 < 4; c4++)
                #pragma unroll
                for (int i = 0; i < 4; i++) {
                    float s = sacc[c4][i];
                    if (diag && (k0 + c4 * 16 + g4 * 4 + i) > qrow) s = -INFINITY;
                    sv[c4][i] = s;
                    smax = fmaxf(smax, s);
                }
            smax = fmaxf(smax, __shfl_xor(smax, 16));
            smax = fmaxf(smax, __shfl_xor(smax, 32));
            float mn = fmaxf(m_i, smax);
            float fs = exp2f((m_i - mn) * SCL);
            float nb = -mn * SCL;
            m_i = mn;
            float rsum = 0.f;
            float pv[4][4];
            #pragma unroll
            for (int c4 = 0; c4 < 4; c4++)
                #pragma unroll
                for (int i = 0; i < 4; i++) {
                    float p = exp2f(fmaf(sv[c4][i], SCL, nb));
                    pv[c4][i] = p;
                    rsum += p;
                }
            rsum += __shfl_xor(rsum, 16);
            rsum += __shfl_xor(rsum, 32);
            l_i = l_i * fs + rsum;
            #pragma unroll
            for (int n4 = 0; n4 < 4; n4++)
                #pragma unroll
                for (int i = 0; i < 4; i++) oacc[n4][i] *= fs;
            #pragma unroll
            for (int c4 = 0; c4 < 4; c4++) {
                union { unsigned short u[4]; unsigned long long ll; } pk;
                #pragma unroll
                for (int i = 0; i < 4; i++) pk.u[i] = f2bf(pv[c4][i]);
                int idx16 = (prow * 64 + c4 * 16 + g4 * 4) ^ pswz;
                *(unsigned long long*)&Ps[idx16] = pk.ll;
            }
            WAITLG0();
            if (pre) {
                union { unsigned short u[8]; bf16x8 v; } w0, w1;
                #pragma unroll
                for (int i2 = 0; i2 < 8; i2++) { w0.u[i2] = vtmp[i2]; w1.u[i2] = vtmp[8 + i2]; }
                int s0 = (vsb * 2) ^ (vd & 7), s1 = (vsb * 2 + 1) ^ (vd & 7);
                *(bf16x8*)&Vt[cur ^ 1][vd * 64 + s0 * 8] = w0.v;
                *(bf16x8*)&Vt[cur ^ 1][vd * 64 + s1 * 8] = w1.v;
            }
            bf16x8 pa[2];
            #pragma unroll
            for (int kk = 0; kk < 2; kk++)
                pa[kk] = *(const bf16x8*)&Ps[(prow * 64 + kk * 32 + g4 * 8) ^ pswz];
            #pragma unroll
            for (int n4 = 0; n4 < 4; n4++) {
                int d = n4 * 16 + r;
                #pragma unroll
                for (int kk = 0; kk < 2; kk++) {
                    bf16x8 vf = *(const bf16x8*)&Vt[cur][d * 64 + (((kk * 4 + g4) ^ (d & 7)) << 3)];
                    oacc[n4] = __builtin_amdgcn_mfma_f32_16x16x32_bf16(vf, pa[kk], oacc[n4], 0, 0, 0);
                }
            }
            __syncthreads();
        }

        float inv = 1.f / l_i;
        #pragma unroll
        for (int n4 = 0; n4 < 4; n4++) {
            union { unsigned short u[4]; unsigned long long ll; } ok;
            #pragma unroll
            for (int i = 0; i < 4; i++) ok.u[i] = f2bf(oacc[n4][i] * inv);
            size_t oidx = ((size_t)(bb * 1024 + qrow)) * 1024 + hh * 64 + n4 * 16 + g4 * 4;
            *(unsigned long long*)&att[oidx] = ok.ll;
        }
    }
}

// ---------------- host ----------------
extern "C" void kernel_launch(void* const* d_in, const int* in_sizes, int n_in,
                              void* d_out, int out_size, void* d_ws, size_t ws_size,
                              hipStream_t stream)
{
    const float* x     = (const float*)d_in[0];
    const float* Wq    = (const float*)d_in[1];
    const float* Wk    = (const float*)d_in[2];
    const float* Wv    = (const float*)d_in[3];
    const float* eq    = (const float*)d_in[4];
    const float* bq    = (const float*)d_in[5];
    const float* ek    = (const float*)d_in[6];
    const float* bk    = (const float*)d_in[7];
    const float* ev    = (const float*)d_in[8];
    const float* bv    = (const float*)d_in[9];
    const float* Wp    = (const float*)d_in[10];
    const float* ep    = (const float*)d_in[11];
    const float* bp    = (const float*)d_in[12];
    const float* biasp = (const float*)d_in[13];
    const float* W1    = (const float*)d_in[14];
    const float* e1    = (const float*)d_in[15];
    const float* b1    = (const float*)d_in[16];
    const float* bias1 = (const float*)d_in[17];
    const float* W2    = (const float*)d_in[18];
    const float* e2    = (const float*)d_in[19];
    const float* b2    = (const float*)d_in[20];
    const float* bias2 = (const float*)d_in[21];
    const float* g1    = (const float*)d_in[22];
    const float* be1   = (const float*)d_in[23];
    const float* g2    = (const float*)d_in[24];
    const float* be2   = (const float*)d_in[25];

    const size_t MB = 1ull << 20;
    char* ws = (char*)d_ws;
    unsigned short* Wqkvq = (unsigned short*)(ws);            //  6 MB
    unsigned short* Wpq   = (unsigned short*)(ws + 6 * MB);   //  2 MB
    unsigned short* W1q   = (unsigned short*)(ws + 8 * MB);   //  8 MB
    unsigned short* W2q   = (unsigned short*)(ws + 16 * MB);  //  8 MB
    unsigned short* hbuf  = (unsigned short*)(ws + 24 * MB);  // 16 MB
    unsigned short* qkvb  = (unsigned short*)(ws + 40 * MB);  // 48 MB; later f (64 MB)
    unsigned short* fbuf  = qkvb;
    unsigned short* attb  = (unsigned short*)(ws + 88 * MB);  // 16 MB
    float*          x2    = (float*)(ws + 104 * MB);          // 32 MB

    quant6_kernel<<<2048, 256, 0, stream>>>(Wq, Wk, Wv, Wp, W1, W2,
                                            eq, ek, ev, ep, e1, e2,
                                            bq, bk, bv, bp, b1, b2,
                                            Wqkvq, Wpq, W1q, W2q);

    ln_kernel<<<8192, 256, 0, stream>>>(x, g1, be1, hbuf);
    // QKV: [8192,3072] bf16, 256^2 8-phase
    gemm256<0><<<dim3(12, 32), 512, 0, stream>>>(hbuf, Wqkvq, 3072, 1024, nullptr, nullptr, nullptr, qkvb);
    // attention (paired q-tiles, swapped-QK softmax)
    attn_kernel<<<dim3(8, 128), 256, 0, stream>>>(qkvb, attb);
    // proj + bias + residual -> x2 (fp32)
    gemm_bt<1><<<dim3(8, 64), 256, 0, stream>>>(attb, Wpq, 1024, 1024, biasp, x, x2, nullptr);
    ln_kernel<<<8192, 256, 0, stream>>>(x2, g2, be2, hbuf);
    // FFN1: relu(h2 W1^T + b1) -> f (bf16), 256^2 8-phase
    gemm256<2><<<dim3(16, 32), 512, 0, stream>>>(hbuf, W1q, 4096, 1024, bias1, nullptr, nullptr, fbuf);
    // FFN2: f W2^T + b2 + x2 -> out (fp32)
    gemm_bt<1><<<dim3(8, 64), 256, 0, stream>>>(fbuf, W2q, 1024, 4096, bias2, x2, (float*)d_out, nullptr);
}

// Round 7
// 329.134 us; speedup vs baseline: 1.5272x; 1.0619x over previous
//
#include <hip/hip_runtime.h>
#include <hip/hip_bf16.h>
#include <math.h>

#define DEVI __device__ __forceinline__

typedef __attribute__((ext_vector_type(8))) short bf16x8;
typedef __attribute__((ext_vector_type(4))) float f32x4;

DEVI unsigned short f2bf(float f) {
    union { float f; unsigned u; } v; v.f = f;
    unsigned r = v.u + 0x7FFFu + ((v.u >> 16) & 1u);
    return (unsigned short)(r >> 16);
}

DEVI unsigned cvtpk(float lo, float hi) {   // D = bf16(hi)<<16 | bf16(lo), RNE
    unsigned d;
    asm volatile("v_cvt_pk_bf16_f32 %0, %1, %2" : "=v"(d) : "v"(lo), "v"(hi));
    return d;
}

DEVI void gload16(const void* g, void* l) {
    __builtin_amdgcn_global_load_lds((const __attribute__((address_space(1))) void*)g,
                                     (__attribute__((address_space(3))) void*)l, 16, 0, 0);
}

#define WAITVM8() asm volatile("s_waitcnt vmcnt(8)" ::: "memory")
#define WAITVM4() asm volatile("s_waitcnt vmcnt(4)" ::: "memory")
#define WAITVM0() asm volatile("s_waitcnt vmcnt(0)" ::: "memory")
#define WAITLG0() asm volatile("s_waitcnt lgkmcnt(0)" ::: "memory")
#define WAITLG8() asm volatile("s_waitcnt lgkmcnt(8)" ::: "memory")
#define BAR()     __builtin_amdgcn_s_barrier()
#define SB()      __builtin_amdgcn_sched_barrier(0)

// ---------------- fused weight fake-quant (all 6 weights, one dispatch) ----------------
__global__ __launch_bounds__(256) void quant6_kernel(
    const float* __restrict__ Wq, const float* __restrict__ Wk, const float* __restrict__ Wv,
    const float* __restrict__ Wp, const float* __restrict__ W1, const float* __restrict__ W2,
    const float* __restrict__ eq, const float* __restrict__ ek, const float* __restrict__ ev,
    const float* __restrict__ ep, const float* __restrict__ e1, const float* __restrict__ e2,
    const float* __restrict__ bq, const float* __restrict__ bk, const float* __restrict__ bv,
    const float* __restrict__ bp, const float* __restrict__ b1, const float* __restrict__ b2,
    unsigned short* __restrict__ Wqkvq, unsigned short* __restrict__ Wpq,
    unsigned short* __restrict__ W1q, unsigned short* __restrict__ W2q)
{
    const int M1 = 1 << 20;
    const int NCH = 3 * M1;  // 12M elems / 4 per chunk
    for (int c = blockIdx.x * blockDim.x + threadIdx.x; c < NCH; c += gridDim.x * blockDim.x) {
        int elem = c * 4;
        const float *W, *e, *b; unsigned short* o; int lgK, local;
        if (elem < M1)            { W = Wq; e = eq; b = bq; o = Wqkvq;          lgK = 10; local = elem; }
        else if (elem < 2 * M1)   { W = Wk; e = ek; b = bk; o = Wqkvq + M1;     lgK = 10; local = elem - M1; }
        else if (elem < 3 * M1)   { W = Wv; e = ev; b = bv; o = Wqkvq + 2 * M1; lgK = 10; local = elem - 2 * M1; }
        else if (elem < 4 * M1)   { W = Wp; e = ep; b = bp; o = Wpq;            lgK = 10; local = elem - 3 * M1; }
        else if (elem < 8 * M1)   { W = W1; e = e1; b = b1; o = W1q;            lgK = 10; local = elem - 4 * M1; }
        else                      { W = W2; e = e2; b = b2; o = W2q;            lgK = 12; local = elem - 8 * M1; }
        int row = local >> lgK;
        float evv = e[row], bvv = b[row];
        float br = fmaxf(bvv, 0.f);
        float mn, mx;
        if (br > 0.f) { float p = exp2f(br - 1.f); mn = -p; mx = p - 1.f; }
        else          { mn = 0.f; mx = 0.f; }
        float si = exp2f(-evv), so = exp2f(evv);
        union { float4 v4; float a[4]; } v;
        v.v4 = *(const float4*)(W + local);
        union { unsigned short u[4]; unsigned long long ll; } ot;
        #pragma unroll
        for (int j = 0; j < 4; j++) {
            float qw = fminf(fmaxf(si * v.a[j], mn), mx);
            ot.u[j] = f2bf(so * rintf(qw));
        }
        *(unsigned long long*)(o + local) = ot.ll;
    }
}

// ---------------- LayerNorm: fp32 in -> bf16 out ----------------
__global__ __launch_bounds__(256) void ln_kernel(
    const float* __restrict__ x, const float* __restrict__ g, const float* __restrict__ be,
    unsigned short* __restrict__ out)
{
    int row = blockIdx.x;
    union { float4 v4; float a[4]; } v;
    v.v4 = ((const float4*)(x + (size_t)row * 1024))[threadIdx.x];
    float s = v.a[0] + v.a[1] + v.a[2] + v.a[3];
    float s2 = v.a[0]*v.a[0] + v.a[1]*v.a[1] + v.a[2]*v.a[2] + v.a[3]*v.a[3];
    #pragma unroll
    for (int off = 32; off > 0; off >>= 1) { s += __shfl_down(s, off); s2 += __shfl_down(s2, off); }
    __shared__ float ps[4], ps2[4];
    int wave = threadIdx.x >> 6, lane = threadIdx.x & 63;
    if (lane == 0) { ps[wave] = s; ps2[wave] = s2; }
    __syncthreads();
    float mu = (ps[0] + ps[1] + ps[2] + ps[3]) * (1.0f / 1024.0f);
    float var = (ps2[0] + ps2[1] + ps2[2] + ps2[3]) * (1.0f / 1024.0f) - mu * mu;
    float rs = rsqrtf(var + 1e-5f);
    int c = threadIdx.x * 4;
    union { unsigned short u[4]; unsigned long long ll; } o;
    #pragma unroll
    for (int j = 0; j < 4; j++) o.u[j] = f2bf((v.a[j] - mu) * rs * g[c + j] + be[c + j]);
    *(unsigned long long*)(out + (size_t)row * 1024 + c) = o.ll;
}

// ---------------- GEMM 128x128, BK=64, double-buffered counted-vmcnt 2-phase ----------------
#define GSTAGE(buf, kt) do { \
    _Pragma("unroll") for (int q_ = 0; q_ < 4; q_++) { \
        int idx_ = q_ * 256 + tid; int row_ = idx_ >> 3; int gs_ = (idx_ & 7) ^ (row_ & 7); \
        gload16(A  + (size_t)(brow + row_) * K + (kt) * 64 + gs_ * 8, &As[buf][idx_ * 8]); \
        gload16(Bw + (size_t)(bcol + row_) * K + (kt) * 64 + gs_ * 8, &Bs[buf][idx_ * 8]); \
    } } while (0)

template<int EP>
__global__ __launch_bounds__(256) void gemm_bt(
    const unsigned short* __restrict__ A, const unsigned short* __restrict__ Bw,
    int N, int K,
    const float* __restrict__ bias, const float* __restrict__ res,
    float* __restrict__ outf, unsigned short* __restrict__ outb)
{
    __shared__ __align__(16) unsigned short As[2][128 * 64];
    __shared__ __align__(16) unsigned short Bs[2][128 * 64];
    int tid = threadIdx.x, lane = tid & 63, wave = tid >> 6;
    int gx = gridDim.x;
    int nwg = gx * gridDim.y;
    int id = blockIdx.y * gx + blockIdx.x;
    int swz = (id & 7) * (nwg >> 3) + (id >> 3);
    int brow = (swz / gx) * 128, bcol = (swz % gx) * 128;
    int wr = wave >> 1, wc = wave & 1;
    int r = lane & 15, g4 = lane >> 4;
    f32x4 acc[4][4];
    #pragma unroll
    for (int i = 0; i < 4; i++)
        #pragma unroll
        for (int j = 0; j < 4; j++) acc[i][j] = (f32x4){0.f, 0.f, 0.f, 0.f};

    int nt = K >> 6;
    GSTAGE(0, 0);
    __syncthreads();
    int cur = 0;
    for (int t = 0; t < nt; ++t) {
        if (t + 1 < nt) { GSTAGE(cur ^ 1, t + 1); WAITVM8(); }
        else            { WAITVM0(); }
        __builtin_amdgcn_s_barrier();
        #pragma unroll
        for (int kk = 0; kk < 2; kk++) {
            bf16x8 af[4], bfr[4];
            #pragma unroll
            for (int mi = 0; mi < 4; mi++) {
                int rh = wr * 64 + mi * 16 + r;
                af[mi] = *(const bf16x8*)&As[cur][rh * 64 + (((kk * 4 + g4) ^ (rh & 7)) << 3)];
            }
            #pragma unroll
            for (int ni = 0; ni < 4; ni++) {
                int rh = wc * 64 + ni * 16 + r;
                bfr[ni] = *(const bf16x8*)&Bs[cur][rh * 64 + (((kk * 4 + g4) ^ (rh & 7)) << 3)];
            }
            #pragma unroll
            for (int mi = 0; mi < 4; mi++)
                #pragma unroll
                for (int ni = 0; ni < 4; ni++)
                    acc[mi][ni] = __builtin_amdgcn_mfma_f32_16x16x32_bf16(af[mi], bfr[ni], acc[mi][ni], 0, 0, 0);
        }
        __builtin_amdgcn_s_barrier();
        cur ^= 1;
    }

    #pragma unroll
    for (int mi = 0; mi < 4; mi++)
        #pragma unroll
        for (int ni = 0; ni < 4; ni++)
            #pragma unroll
            for (int i = 0; i < 4; i++) {
                int row = brow + wr * 64 + mi * 16 + g4 * 4 + i;
                int col = bcol + wc * 64 + ni * 16 + r;
                float v = acc[mi][ni][i];
                if (EP == 0) {
                    outb[(size_t)row * N + col] = f2bf(v);
                } else if (EP == 1) {
                    outf[(size_t)row * N + col] = v + bias[col] + res[(size_t)row * N + col];
                } else {
                    outb[(size_t)row * N + col] = f2bf(fmaxf(v + bias[col], 0.f));
                }
            }
}

// ---------------- GEMM 256x256 8-phase (ledger-verified; ran clean r6) ----------------
#define STAGE_A(b, h, kt) do { \
    _Pragma("unroll") \
    for (int ld = 0; ld < 2; ld++) { \
        int idx = ld * 512 + tid; int rw = idx >> 3; int gs = (idx & 7) ^ (rw & 7); \
        gload16(Aa + (size_t)(brow + (h) * 128 + rw) * K + (kt) * 64 + gs * 8, &As[b][h][idx * 8]); \
    } } while (0)

#define STAGE_B(b, h, kt) do { \
    _Pragma("unroll") \
    for (int ld = 0; ld < 2; ld++) { \
        int idx = ld * 512 + tid; int rw = idx >> 3; int gs = (idx & 7) ^ (rw & 7); \
        gload16(Bw + (size_t)(bcol + (h) * 128 + rw) * K + (kt) * 64 + gs * 8, &Bs[b][h][idx * 8]); \
    } } while (0)

#define RD_A(b, mh) do { \
    _Pragma("unroll") for (int mi = 0; mi < 4; mi++) \
    _Pragma("unroll") for (int kk = 0; kk < 2; kk++) { \
        int rh = (mh) * 64 + mi * 16 + r; \
        af[mi][kk] = *(const bf16x8*)&As[b][wr][rh * 64 + (((kk * 4 + g4) ^ (rh & 7)) << 3)]; \
    } } while (0)

#define RD_B2(b, nh) do { \
    _Pragma("unroll") for (int nj = 0; nj < 2; nj++) \
    _Pragma("unroll") for (int kk = 0; kk < 2; kk++) { \
        int rh = (wc & 1) * 64 + ((nh) * 2 + nj) * 16 + r; \
        bfr[(nh) * 2 + nj][kk] = *(const bf16x8*)&Bs[b][wc >> 1][rh * 64 + (((kk * 4 + g4) ^ (rh & 7)) << 3)]; \
    } } while (0)

#define QUAD(mh, nh) do { \
    __builtin_amdgcn_s_setprio(1); \
    _Pragma("unroll") for (int mi = 0; mi < 4; mi++) \
    _Pragma("unroll") for (int nj = 0; nj < 2; nj++) \
    _Pragma("unroll") for (int kk = 0; kk < 2; kk++) \
        acc[(mh) * 4 + mi][(nh) * 2 + nj] = __builtin_amdgcn_mfma_f32_16x16x32_bf16( \
            af[mi][kk], bfr[(nh) * 2 + nj][kk], acc[(mh) * 4 + mi][(nh) * 2 + nj], 0, 0, 0); \
    __builtin_amdgcn_s_setprio(0); \
    } while (0)

template<int EP>
__global__ __launch_bounds__(512, 2) void gemm256(
    const unsigned short* __restrict__ Aa, const unsigned short* __restrict__ Bw,
    int N, int K,
    const float* __restrict__ bias, const float* __restrict__ res,
    float* __restrict__ outf, unsigned short* __restrict__ outb)
{
    __shared__ __align__(16) unsigned short As[2][2][128 * 64];
    __shared__ __align__(16) unsigned short Bs[2][2][128 * 64];
    int tid = threadIdx.x, lane = tid & 63, wave = tid >> 6;
    int gx = gridDim.x;
    int nwg = gx * gridDim.y;
    int id = blockIdx.y * gx + blockIdx.x;
    int swz = (id & 7) * (nwg >> 3) + (id >> 3);
    int brow = (swz / gx) * 256, bcol = (swz % gx) * 256;
    int wr = wave >> 2, wc = wave & 3;
    int r = lane & 15, g4 = lane >> 4;
    int KT = K >> 6;

    f32x4 acc[8][4];
    #pragma unroll
    for (int i = 0; i < 8; i++)
        #pragma unroll
        for (int j = 0; j < 4; j++) acc[i][j] = (f32x4){0.f, 0.f, 0.f, 0.f};
    bf16x8 af[4][2], bfr[4][2];

    STAGE_A(0, 0, 0); STAGE_A(0, 1, 0); STAGE_B(0, 0, 0); STAGE_B(0, 1, 0);
    STAGE_B(1, 0, 1); STAGE_B(1, 1, 1);
    WAITVM4();
    BAR();

    for (int t = 0; t < KT; t += 2) {
        RD_A(0, 0); RD_B2(0, 0);
        STAGE_A(1, 0, t + 1);
        WAITLG8();
        BAR(); WAITLG0(); SB();
        QUAD(0, 0);
        BAR();
        RD_B2(0, 1);
        STAGE_A(1, 1, t + 1);
        BAR(); WAITLG0(); SB();
        QUAD(0, 1);
        BAR();
        RD_A(0, 1);
        if (t + 2 < KT) STAGE_B(0, 0, t + 2);
        BAR(); WAITLG0(); SB();
        QUAD(1, 1);
        BAR();
        if (t + 2 < KT) { STAGE_B(0, 1, t + 2); WAITVM4(); } else { WAITVM0(); }
        BAR(); WAITLG0(); SB();
        QUAD(1, 0);
        BAR();
        RD_A(1, 0); RD_B2(1, 0);
        if (t + 2 < KT) STAGE_A(0, 0, t + 2);
        WAITLG8();
        BAR(); WAITLG0(); SB();
        QUAD(0, 0);
        BAR();
        RD_B2(1, 1);
        if (t + 2 < KT) STAGE_A(0, 1, t + 2);
        BAR(); WAITLG0(); SB();
        QUAD(0, 1);
        BAR();
        RD_A(1, 1);
        if (t + 3 < KT) STAGE_B(1, 0, t + 3);
        BAR(); WAITLG0(); SB();
        QUAD(1, 1);
        BAR();
        if (t + 3 < KT) { STAGE_B(1, 1, t + 3); WAITVM4(); } else { WAITVM0(); }
        BAR(); WAITLG0(); SB();
        QUAD(1, 0);
        BAR();
    }

    #pragma unroll
    for (int m = 0; m < 8; m++)
        #pragma unroll
        for (int n = 0; n < 4; n++)
            #pragma unroll
            for (int j = 0; j < 4; j++) {
                int row = brow + wr * 128 + m * 16 + g4 * 4 + j;
                int col = bcol + wc * 64 + n * 16 + r;
                float v = acc[m][n][j];
                if (EP == 0) {
                    outb[(size_t)row * N + col] = f2bf(v);
                } else if (EP == 1) {
                    outf[(size_t)row * N + col] = v + bias[col] + res[(size_t)row * N + col];
                } else {
                    outb[(size_t)row * N + col] = f2bf(fmaxf(v + bias[col], 0.f));
                }
            }
}

// ---------------- Flash attention: 8 waves, 2 q-tiles share staged K/V ----------------
// Supertile s = q-tiles {2s, 2s+1}; block pi handles s=pi then s=7-pi (uniform 18 stages).
// Waves 0-3 -> q-tile 2s, waves 4-7 -> 2s+1. Swapped QK^T, in-lane softmax, T13 defer-max,
// cvt_pk bf16 packs, Vt stride 66 (bank-conflict-free write+read).
__global__ __launch_bounds__(512, 4) void attn_kernel(
    const unsigned short* __restrict__ qkv, unsigned short* __restrict__ att)
{
    __shared__ __align__(16) unsigned short Ks[2][64 * 64];
    __shared__ __align__(16) unsigned short Vt[2][64 * 66];
    __shared__ __align__(16) unsigned short Ps[2][64 * 64];
    int tid = threadIdx.x, lane = tid & 63, w = tid >> 6;
    int half = w >> 2;
    int pi = blockIdx.x;                       // 0..3
    int bh = blockIdx.y, bb = bh >> 4, hh = bh & 15;
    int r = lane & 15, g4 = lane >> 4;
    const unsigned short* base = qkv + (size_t)bb * 1024 * 3072;
    const float SCL = 0.03125f * 1.4426950408889634f;
    int vd = tid & 63, vsb = tid >> 6;         // V transpose: 8 rows per thread
    int prow = (w & 3) * 16 + r;
    int pswz = (r & 7) << 3;

    for (int sidx = 0; sidx < 2; sidx++) {
        int s = sidx ? (7 - pi) : pi;
        int qt = 2 * s + half;                 // this half's q-tile
        int qtmax = 2 * s + 1;                 // block-level max
        int qrow = qt * 64 + prow;

        bf16x8 qf[2];
        #pragma unroll
        for (int kk = 0; kk < 2; kk++)
            qf[kk] = *(const bf16x8*)&base[(size_t)qrow * 3072 + hh * 64 + kk * 32 + g4 * 8];

        f32x4 oacc[4];
        #pragma unroll
        for (int i = 0; i < 4; i++) oacc[i] = (f32x4){0.f, 0.f, 0.f, 0.f};
        float m_i = -INFINITY, l_i = 0.f;

        unsigned short vtmp[8];
        // prologue: stage tile 0 (previous supertile's reads all completed at its last barrier)
        {
            int row = tid >> 3, slot = tid & 7;
            int gs = slot ^ (row & 7);
            gload16(base + (size_t)row * 3072 + 1024 + hh * 64 + gs * 8, &Ks[0][tid * 8]);
            #pragma unroll
            for (int i2 = 0; i2 < 8; i2++)
                vtmp[i2] = base[(size_t)(vsb * 8 + i2) * 3072 + 2048 + hh * 64 + vd];
            union { unsigned short u[8]; bf16x8 v; } w0;
            #pragma unroll
            for (int i2 = 0; i2 < 8; i2++) w0.u[i2] = vtmp[i2];
            *(bf16x8*)&Vt[0][vd * 66 + (vsb ^ (vd & 7)) * 8] = w0.v;
        }
        __syncthreads();

        for (int ki = 0; ki <= qtmax; ki++) {
            int cur = ki & 1;
            bool pre = (ki < qtmax);
            bool act = (ki <= qt);
            if (pre) {
                int k1 = (ki + 1) * 64;
                int row = tid >> 3, slot = tid & 7;
                int gs = slot ^ (row & 7);
                gload16(base + (size_t)(k1 + row) * 3072 + 1024 + hh * 64 + gs * 8, &Ks[cur ^ 1][tid * 8]);
                #pragma unroll
                for (int i2 = 0; i2 < 8; i2++)
                    vtmp[i2] = base[(size_t)(k1 + vsb * 8 + i2) * 3072 + 2048 + hh * 64 + vd];
            }

            if (act) {
                int k0 = ki * 64;
                // S^T = K Q^T: lane owns q-row qrow, 16 k-values per tile
                f32x4 sacc[4];
                #pragma unroll
                for (int c4 = 0; c4 < 4; c4++) sacc[c4] = (f32x4){0.f, 0.f, 0.f, 0.f};
                #pragma unroll
                for (int c4 = 0; c4 < 4; c4++) {
                    int krow = c4 * 16 + r;
                    #pragma unroll
                    for (int kk = 0; kk < 2; kk++) {
                        int slot = (g4 + kk * 4) ^ (krow & 7);
                        bf16x8 kf = *(const bf16x8*)&Ks[cur][krow * 64 + slot * 8];
                        sacc[c4] = __builtin_amdgcn_mfma_f32_16x16x32_bf16(kf, qf[kk], sacc[c4], 0, 0, 0);
                    }
                }
                bool diag = (ki == qt);
                float sv[4][4];
                float smax = -INFINITY;
                #pragma unroll
                for (int c4 = 0; c4 < 4; c4++)
                    #pragma unroll
                    for (int i = 0; i < 4; i++) {
                        float sa = sacc[c4][i];
                        if (diag && (k0 + c4 * 16 + g4 * 4 + i) > qrow) sa = -INFINITY;
                        sv[c4][i] = sa;
                        smax = fmaxf(smax, sa);
                    }
                smax = fmaxf(smax, __shfl_xor(smax, 16));
                smax = fmaxf(smax, __shfl_xor(smax, 32));
                // T13 defer-max: rescale only when growth > 8 (exp2 domain)
                if (!__all((smax - m_i) * SCL <= 8.f)) {
                    float mn = fmaxf(m_i, smax);
                    float fs = exp2f((m_i - mn) * SCL);
                    m_i = mn;
                    l_i *= fs;
                    #pragma unroll
                    for (int n4 = 0; n4 < 4; n4++)
                        #pragma unroll
                        for (int i = 0; i < 4; i++) oacc[n4][i] *= fs;
                }
                float nb = -m_i * SCL;
                float rsum = 0.f;
                float pv[4][4];
                #pragma unroll
                for (int c4 = 0; c4 < 4; c4++)
                    #pragma unroll
                    for (int i = 0; i < 4; i++) {
                        float p = exp2f(fmaf(sv[c4][i], SCL, nb));
                        pv[c4][i] = p;
                        rsum += p;
                    }
                rsum += __shfl_xor(rsum, 16);
                rsum += __shfl_xor(rsum, 32);
                l_i += rsum;
                // pack P -> Ps[half] (lane-private rows, wave-level lgkm ordering)
                #pragma unroll
                for (int c4 = 0; c4 < 4; c4++) {
                    unsigned long long ll = (unsigned long long)cvtpk(pv[c4][0], pv[c4][1])
                                          | ((unsigned long long)cvtpk(pv[c4][2], pv[c4][3]) << 32);
                    *(unsigned long long*)&Ps[half][(prow * 64 + c4 * 16 + g4 * 4) ^ pswz] = ll;
                }
                WAITLG0();
            }
            if (pre) {
                union { unsigned short u[8]; bf16x8 v; } w0;
                #pragma unroll
                for (int i2 = 0; i2 < 8; i2++) w0.u[i2] = vtmp[i2];
                *(bf16x8*)&Vt[cur ^ 1][vd * 66 + (vsb ^ (vd & 7)) * 8] = w0.v;
            }
            if (act) {
                bf16x8 pa[2];
                #pragma unroll
                for (int kk = 0; kk < 2; kk++)
                    pa[kk] = *(const bf16x8*)&Ps[half][(prow * 64 + kk * 32 + g4 * 8) ^ pswz];
                #pragma unroll
                for (int n4 = 0; n4 < 4; n4++) {
                    int d = n4 * 16 + r;
                    #pragma unroll
                    for (int kk = 0; kk < 2; kk++) {
                        bf16x8 vf = *(const bf16x8*)&Vt[cur][d * 66 + (((kk * 4 + g4) ^ (d & 7)) << 3)];
                        oacc[n4] = __builtin_amdgcn_mfma_f32_16x16x32_bf16(vf, pa[kk], oacc[n4], 0, 0, 0);
                    }
                }
            }
            __syncthreads();   // drains vmcnt (K gload) + lgkm (V ds_write); buffers consistent
        }

        float inv = 1.f / l_i;
        #pragma unroll
        for (int n4 = 0; n4 < 4; n4++) {
            unsigned long long ll = (unsigned long long)cvtpk(oacc[n4][0] * inv, oacc[n4][1] * inv)
                                  | ((unsigned long long)cvtpk(oacc[n4][2] * inv, oacc[n4][3] * inv) << 32);
            size_t oidx = ((size_t)(bb * 1024 + qrow)) * 1024 + hh * 64 + n4 * 16 + g4 * 4;
            *(unsigned long long*)&att[oidx] = ll;
        }
    }
}

// ---------------- host ----------------
extern "C" void kernel_launch(void* const* d_in, const int* in_sizes, int n_in,
                              void* d_out, int out_size, void* d_ws, size_t ws_size,
                              hipStream_t stream)
{
    const float* x     = (const float*)d_in[0];
    const float* Wq    = (const float*)d_in[1];
    const float* Wk    = (const float*)d_in[2];
    const float* Wv    = (const float*)d_in[3];
    const float* eq    = (const float*)d_in[4];
    const float* bq    = (const float*)d_in[5];
    const float* ek    = (const float*)d_in[6];
    const float* bk    = (const float*)d_in[7];
    const float* ev    = (const float*)d_in[8];
    const float* bv    = (const float*)d_in[9];
    const float* Wp    = (const float*)d_in[10];
    const float* ep    = (const float*)d_in[11];
    const float* bp    = (const float*)d_in[12];
    const float* biasp = (const float*)d_in[13];
    const float* W1    = (const float*)d_in[14];
    const float* e1    = (const float*)d_in[15];
    const float* b1    = (const float*)d_in[16];
    const float* bias1 = (const float*)d_in[17];
    const float* W2    = (const float*)d_in[18];
    const float* e2    = (const float*)d_in[19];
    const float* b2    = (const float*)d_in[20];
    const float* bias2 = (const float*)d_in[21];
    const float* g1    = (const float*)d_in[22];
    const float* be1   = (const float*)d_in[23];
    const float* g2    = (const float*)d_in[24];
    const float* be2   = (const float*)d_in[25];

    const size_t MB = 1ull << 20;
    char* ws = (char*)d_ws;
    unsigned short* Wqkvq = (unsigned short*)(ws);            //  6 MB
    unsigned short* Wpq   = (unsigned short*)(ws + 6 * MB);   //  2 MB
    unsigned short* W1q   = (unsigned short*)(ws + 8 * MB);   //  8 MB
    unsigned short* W2q   = (unsigned short*)(ws + 16 * MB);  //  8 MB
    unsigned short* hbuf  = (unsigned short*)(ws + 24 * MB);  // 16 MB
    unsigned short* qkvb  = (unsigned short*)(ws + 40 * MB);  // 48 MB; later f (64 MB)
    unsigned short* fbuf  = qkvb;
    unsigned short* attb  = (unsigned short*)(ws + 88 * MB);  // 16 MB
    float*          x2    = (float*)(ws + 104 * MB);          // 32 MB

    quant6_kernel<<<2048, 256, 0, stream>>>(Wq, Wk, Wv, Wp, W1, W2,
                                            eq, ek, ev, ep, e1, e2,
                                            bq, bk, bv, bp, b1, b2,
                                            Wqkvq, Wpq, W1q, W2q);

    ln_kernel<<<8192, 256, 0, stream>>>(x, g1, be1, hbuf);
    // QKV: [8192,3072] bf16, 256^2 8-phase
    gemm256<0><<<dim3(12, 32), 512, 0, stream>>>(hbuf, Wqkvq, 3072, 1024, nullptr, nullptr, nullptr, qkvb);
    // attention (8-wave shared staging, supertile-paired)
    attn_kernel<<<dim3(4, 128), 512, 0, stream>>>(qkvb, attb);
    // proj + bias + residual -> x2 (fp32)
    gemm_bt<1><<<dim3(8, 64), 256, 0, stream>>>(attb, Wpq, 1024, 1024, biasp, x, x2, nullptr);
    ln_kernel<<<8192, 256, 0, stream>>>(x2, g2, be2, hbuf);
    // FFN1: relu(h2 W1^T + b1) -> f (bf16), 256^2 8-phase
    gemm256<2><<<dim3(16, 32), 512, 0, stream>>>(hbuf, W1q, 4096, 1024, bias1, nullptr, nullptr, fbuf);
    // FFN2: f W2^T + b2 + x2 -> out (fp32)
    gemm_bt<1><<<dim3(8, 64), 256, 0, stream>>>(fbuf, W2q, 1024, 4096, bias2, x2, (float*)d_out, nullptr);
}

// Round 8
// 322.304 us; speedup vs baseline: 1.5596x; 1.0212x over previous
//
#include <hip/hip_runtime.h>
#include <hip/hip_bf16.h>
#include <math.h>

#define DEVI __device__ __forceinline__

typedef __attribute__((ext_vector_type(8))) short bf16x8;
typedef __attribute__((ext_vector_type(4))) float f32x4;

DEVI unsigned short f2bf(float f) {
    union { float f; unsigned u; } v; v.f = f;
    unsigned r = v.u + 0x7FFFu + ((v.u >> 16) & 1u);
    return (unsigned short)(r >> 16);
}

DEVI float bf2f(unsigned short u) {
    union { unsigned u; float f; } v; v.u = (unsigned)u << 16; return v.f;
}

DEVI unsigned cvtpk(float lo, float hi) {   // D = bf16(hi)<<16 | bf16(lo), RNE
    unsigned d;
    asm volatile("v_cvt_pk_bf16_f32 %0, %1, %2" : "=v"(d) : "v"(lo), "v"(hi));
    return d;
}

DEVI void gload16(const void* g, void* l) {
    __builtin_amdgcn_global_load_lds((const __attribute__((address_space(1))) void*)g,
                                     (__attribute__((address_space(3))) void*)l, 16, 0, 0);
}

#define WAITVM8() asm volatile("s_waitcnt vmcnt(8)" ::: "memory")
#define WAITVM4() asm volatile("s_waitcnt vmcnt(4)" ::: "memory")
#define WAITVM0() asm volatile("s_waitcnt vmcnt(0)" ::: "memory")
#define WAITLG0() asm volatile("s_waitcnt lgkmcnt(0)" ::: "memory")
#define WAITLG8() asm volatile("s_waitcnt lgkmcnt(8)" ::: "memory")
#define BAR()     __builtin_amdgcn_s_barrier()
#define SB()      __builtin_amdgcn_sched_barrier(0)

// ---------------- fused pre-pass: 6 weight fake-quants + LN1, one dispatch ----------------
// Blocks [0,2048): quant grid-stride. Blocks [2048,4096): LN1 wave-per-row (4 rows/block).
__global__ __launch_bounds__(256) void fused_pre_kernel(
    const float* __restrict__ Wq, const float* __restrict__ Wk, const float* __restrict__ Wv,
    const float* __restrict__ Wp, const float* __restrict__ W1, const float* __restrict__ W2,
    const float* __restrict__ eq, const float* __restrict__ ek, const float* __restrict__ ev,
    const float* __restrict__ ep, const float* __restrict__ e1, const float* __restrict__ e2,
    const float* __restrict__ bq, const float* __restrict__ bk, const float* __restrict__ bv,
    const float* __restrict__ bp, const float* __restrict__ b1, const float* __restrict__ b2,
    unsigned short* __restrict__ Wqkvq, unsigned short* __restrict__ Wpq,
    unsigned short* __restrict__ W1q, unsigned short* __restrict__ W2q,
    const float* __restrict__ x, const float* __restrict__ g1, const float* __restrict__ be1,
    unsigned short* __restrict__ hbuf)
{
    const int M1 = 1 << 20;
    if (blockIdx.x < 2048) {
        const int NCH = 3 * M1;  // 12M elems / 4 per chunk
        const int STRIDE = 2048 * 256;
        for (int c = blockIdx.x * blockDim.x + threadIdx.x; c < NCH; c += STRIDE) {
            int elem = c * 4;
            const float *W, *e, *b; unsigned short* o; int lgK, local;
            if (elem < M1)            { W = Wq; e = eq; b = bq; o = Wqkvq;          lgK = 10; local = elem; }
            else if (elem < 2 * M1)   { W = Wk; e = ek; b = bk; o = Wqkvq + M1;     lgK = 10; local = elem - M1; }
            else if (elem < 3 * M1)   { W = Wv; e = ev; b = bv; o = Wqkvq + 2 * M1; lgK = 10; local = elem - 2 * M1; }
            else if (elem < 4 * M1)   { W = Wp; e = ep; b = bp; o = Wpq;            lgK = 10; local = elem - 3 * M1; }
            else if (elem < 8 * M1)   { W = W1; e = e1; b = b1; o = W1q;            lgK = 10; local = elem - 4 * M1; }
            else                      { W = W2; e = e2; b = b2; o = W2q;            lgK = 12; local = elem - 8 * M1; }
            int row = local >> lgK;
            float evv = e[row], bvv = b[row];
            float br = fmaxf(bvv, 0.f);
            float mn, mx;
            if (br > 0.f) { float p = exp2f(br - 1.f); mn = -p; mx = p - 1.f; }
            else          { mn = 0.f; mx = 0.f; }
            float si = exp2f(-evv), so = exp2f(evv);
            union { float4 v4; float a[4]; } v;
            v.v4 = *(const float4*)(W + local);
            union { unsigned short u[4]; unsigned long long ll; } ot;
            #pragma unroll
            for (int j = 0; j < 4; j++) {
                float qw = fminf(fmaxf(si * v.a[j], mn), mx);
                ot.u[j] = f2bf(so * rintf(qw));
            }
            *(unsigned long long*)(o + local) = ot.ll;
        }
    } else {
        int row = (blockIdx.x - 2048) * 4 + (threadIdx.x >> 6);
        int lane = threadIdx.x & 63;
        const float* xp = x + (size_t)row * 1024 + lane * 16;
        float a[16];
        #pragma unroll
        for (int j = 0; j < 4; j++) {
            float4 v = *(const float4*)(xp + j * 4);
            a[j * 4] = v.x; a[j * 4 + 1] = v.y; a[j * 4 + 2] = v.z; a[j * 4 + 3] = v.w;
        }
        float s = 0.f, s2 = 0.f;
        #pragma unroll
        for (int i = 0; i < 16; i++) { s += a[i]; s2 += a[i] * a[i]; }
        #pragma unroll
        for (int off = 1; off < 64; off <<= 1) { s += __shfl_xor(s, off); s2 += __shfl_xor(s2, off); }
        float mu = s * (1.0f / 1024.0f);
        float var = s2 * (1.0f / 1024.0f) - mu * mu;
        float rs = rsqrtf(var + 1e-5f);
        int c0 = lane * 16;
        float r[16];
        #pragma unroll
        for (int i = 0; i < 16; i++) r[i] = (a[i] - mu) * rs * g1[c0 + i] + be1[c0 + i];
        unsigned w[8];
        #pragma unroll
        for (int j = 0; j < 8; j++) w[j] = cvtpk(r[2 * j], r[2 * j + 1]);
        unsigned short* op = hbuf + (size_t)row * 1024 + c0;
        *(uint4*)(op)     = *(uint4*)&w[0];
        *(uint4*)(op + 8) = *(uint4*)&w[4];
    }
}

// ---------------- LayerNorm wave-per-row, bf16 in -> bf16 out (for LN2) ----------------
__global__ __launch_bounds__(256) void ln_bf_kernel(
    const unsigned short* __restrict__ xb, const float* __restrict__ g, const float* __restrict__ be,
    unsigned short* __restrict__ out)
{
    int row = blockIdx.x * 4 + (threadIdx.x >> 6);
    int lane = threadIdx.x & 63;
    const unsigned short* xp = xb + (size_t)row * 1024 + lane * 16;
    float a[16];
    #pragma unroll
    for (int j = 0; j < 2; j++) {
        bf16x8 v = *(const bf16x8*)(xp + j * 8);
        #pragma unroll
        for (int i = 0; i < 8; i++) a[j * 8 + i] = bf2f(((unsigned short*)&v)[i]);
    }
    float s = 0.f, s2 = 0.f;
    #pragma unroll
    for (int i = 0; i < 16; i++) { s += a[i]; s2 += a[i] * a[i]; }
    #pragma unroll
    for (int off = 1; off < 64; off <<= 1) { s += __shfl_xor(s, off); s2 += __shfl_xor(s2, off); }
    float mu = s * (1.0f / 1024.0f);
    float var = s2 * (1.0f / 1024.0f) - mu * mu;
    float rs = rsqrtf(var + 1e-5f);
    int c0 = lane * 16;
    float r[16];
    #pragma unroll
    for (int i = 0; i < 16; i++) r[i] = (a[i] - mu) * rs * g[c0 + i] + be[c0 + i];
    unsigned w[8];
    #pragma unroll
    for (int j = 0; j < 8; j++) w[j] = cvtpk(r[2 * j], r[2 * j + 1]);
    unsigned short* op = out + (size_t)row * 1024 + c0;
    *(uint4*)(op)     = *(uint4*)&w[0];
    *(uint4*)(op + 8) = *(uint4*)&w[4];
}

// ---------------- GEMM 128x128, BK=64, double-buffered counted-vmcnt 2-phase ----------------
// EP 0: bf16 plain. EP 1: fp32 = acc+bias+res(f32). EP 2: bf16 relu(acc+bias).
// EP 3: bf16 = acc+bias+res(f32). EP 4: fp32 = acc+bias+resb(bf16).
#define GSTAGE(buf, kt) do { \
    _Pragma("unroll") for (int q_ = 0; q_ < 4; q_++) { \
        int idx_ = q_ * 256 + tid; int row_ = idx_ >> 3; int gs_ = (idx_ & 7) ^ (row_ & 7); \
        gload16(A  + (size_t)(brow + row_) * K + (kt) * 64 + gs_ * 8, &As[buf][idx_ * 8]); \
        gload16(Bw + (size_t)(bcol + row_) * K + (kt) * 64 + gs_ * 8, &Bs[buf][idx_ * 8]); \
    } } while (0)

template<int EP>
__global__ __launch_bounds__(256) void gemm_bt(
    const unsigned short* __restrict__ A, const unsigned short* __restrict__ Bw,
    int N, int K,
    const float* __restrict__ bias, const float* __restrict__ res,
    const unsigned short* __restrict__ resb,
    float* __restrict__ outf, unsigned short* __restrict__ outb)
{
    __shared__ __align__(16) unsigned short As[2][128 * 64];
    __shared__ __align__(16) unsigned short Bs[2][128 * 64];
    int tid = threadIdx.x, lane = tid & 63, wave = tid >> 6;
    int gx = gridDim.x;
    int nwg = gx * gridDim.y;
    int id = blockIdx.y * gx + blockIdx.x;
    int swz = (id & 7) * (nwg >> 3) + (id >> 3);
    int brow = (swz / gx) * 128, bcol = (swz % gx) * 128;
    int wr = wave >> 1, wc = wave & 1;
    int r = lane & 15, g4 = lane >> 4;
    f32x4 acc[4][4];
    #pragma unroll
    for (int i = 0; i < 4; i++)
        #pragma unroll
        for (int j = 0; j < 4; j++) acc[i][j] = (f32x4){0.f, 0.f, 0.f, 0.f};

    int nt = K >> 6;
    GSTAGE(0, 0);
    __syncthreads();
    int cur = 0;
    for (int t = 0; t < nt; ++t) {
        if (t + 1 < nt) { GSTAGE(cur ^ 1, t + 1); WAITVM8(); }
        else            { WAITVM0(); }
        __builtin_amdgcn_s_barrier();
        #pragma unroll
        for (int kk = 0; kk < 2; kk++) {
            bf16x8 af[4], bfr[4];
            #pragma unroll
            for (int mi = 0; mi < 4; mi++) {
                int rh = wr * 64 + mi * 16 + r;
                af[mi] = *(const bf16x8*)&As[cur][rh * 64 + (((kk * 4 + g4) ^ (rh & 7)) << 3)];
            }
            #pragma unroll
            for (int ni = 0; ni < 4; ni++) {
                int rh = wc * 64 + ni * 16 + r;
                bfr[ni] = *(const bf16x8*)&Bs[cur][rh * 64 + (((kk * 4 + g4) ^ (rh & 7)) << 3)];
            }
            #pragma unroll
            for (int mi = 0; mi < 4; mi++)
                #pragma unroll
                for (int ni = 0; ni < 4; ni++)
                    acc[mi][ni] = __builtin_amdgcn_mfma_f32_16x16x32_bf16(af[mi], bfr[ni], acc[mi][ni], 0, 0, 0);
        }
        __builtin_amdgcn_s_barrier();
        cur ^= 1;
    }

    #pragma unroll
    for (int mi = 0; mi < 4; mi++)
        #pragma unroll
        for (int ni = 0; ni < 4; ni++)
            #pragma unroll
            for (int i = 0; i < 4; i++) {
                int row = brow + wr * 64 + mi * 16 + g4 * 4 + i;
                int col = bcol + wc * 64 + ni * 16 + r;
                float v = acc[mi][ni][i];
                if (EP == 0) {
                    outb[(size_t)row * N + col] = f2bf(v);
                } else if (EP == 1) {
                    outf[(size_t)row * N + col] = v + bias[col] + res[(size_t)row * N + col];
                } else if (EP == 2) {
                    outb[(size_t)row * N + col] = f2bf(fmaxf(v + bias[col], 0.f));
                } else if (EP == 3) {
                    outb[(size_t)row * N + col] = f2bf(v + bias[col] + res[(size_t)row * N + col]);
                } else {
                    outf[(size_t)row * N + col] = v + bias[col] + bf2f(resb[(size_t)row * N + col]);
                }
            }
}

// ---------------- GEMM 256x256 8-phase (ledger-verified; clean r6/r7) ----------------
#define STAGE_A(b, h, kt) do { \
    _Pragma("unroll") \
    for (int ld = 0; ld < 2; ld++) { \
        int idx = ld * 512 + tid; int rw = idx >> 3; int gs = (idx & 7) ^ (rw & 7); \
        gload16(Aa + (size_t)(brow + (h) * 128 + rw) * K + (kt) * 64 + gs * 8, &As[b][h][idx * 8]); \
    } } while (0)

#define STAGE_B(b, h, kt) do { \
    _Pragma("unroll") \
    for (int ld = 0; ld < 2; ld++) { \
        int idx = ld * 512 + tid; int rw = idx >> 3; int gs = (idx & 7) ^ (rw & 7); \
        gload16(Bw + (size_t)(bcol + (h) * 128 + rw) * K + (kt) * 64 + gs * 8, &Bs[b][h][idx * 8]); \
    } } while (0)

#define RD_A(b, mh) do { \
    _Pragma("unroll") for (int mi = 0; mi < 4; mi++) \
    _Pragma("unroll") for (int kk = 0; kk < 2; kk++) { \
        int rh = (mh) * 64 + mi * 16 + r; \
        af[mi][kk] = *(const bf16x8*)&As[b][wr][rh * 64 + (((kk * 4 + g4) ^ (rh & 7)) << 3)]; \
    } } while (0)

#define RD_B2(b, nh) do { \
    _Pragma("unroll") for (int nj = 0; nj < 2; nj++) \
    _Pragma("unroll") for (int kk = 0; kk < 2; kk++) { \
        int rh = (wc & 1) * 64 + ((nh) * 2 + nj) * 16 + r; \
        bfr[(nh) * 2 + nj][kk] = *(const bf16x8*)&Bs[b][wc >> 1][rh * 64 + (((kk * 4 + g4) ^ (rh & 7)) << 3)]; \
    } } while (0)

#define QUAD(mh, nh) do { \
    __builtin_amdgcn_s_setprio(1); \
    _Pragma("unroll") for (int mi = 0; mi < 4; mi++) \
    _Pragma("unroll") for (int nj = 0; nj < 2; nj++) \
    _Pragma("unroll") for (int kk = 0; kk < 2; kk++) \
        acc[(mh) * 4 + mi][(nh) * 2 + nj] = __builtin_amdgcn_mfma_f32_16x16x32_bf16( \
            af[mi][kk], bfr[(nh) * 2 + nj][kk], acc[(mh) * 4 + mi][(nh) * 2 + nj], 0, 0, 0); \
    __builtin_amdgcn_s_setprio(0); \
    } while (0)

template<int EP>
__global__ __launch_bounds__(512, 2) void gemm256(
    const unsigned short* __restrict__ Aa, const unsigned short* __restrict__ Bw,
    int N, int K,
    const float* __restrict__ bias, const float* __restrict__ res,
    float* __restrict__ outf, unsigned short* __restrict__ outb)
{
    __shared__ __align__(16) unsigned short As[2][2][128 * 64];
    __shared__ __align__(16) unsigned short Bs[2][2][128 * 64];
    int tid = threadIdx.x, lane = tid & 63, wave = tid >> 6;
    int gx = gridDim.x;
    int nwg = gx * gridDim.y;
    int id = blockIdx.y * gx + blockIdx.x;
    int swz = (id & 7) * (nwg >> 3) + (id >> 3);
    int brow = (swz / gx) * 256, bcol = (swz % gx) * 256;
    int wr = wave >> 2, wc = wave & 3;
    int r = lane & 15, g4 = lane >> 4;
    int KT = K >> 6;

    f32x4 acc[8][4];
    #pragma unroll
    for (int i = 0; i < 8; i++)
        #pragma unroll
        for (int j = 0; j < 4; j++) acc[i][j] = (f32x4){0.f, 0.f, 0.f, 0.f};
    bf16x8 af[4][2], bfr[4][2];

    STAGE_A(0, 0, 0); STAGE_A(0, 1, 0); STAGE_B(0, 0, 0); STAGE_B(0, 1, 0);
    STAGE_B(1, 0, 1); STAGE_B(1, 1, 1);
    WAITVM4();
    BAR();

    for (int t = 0; t < KT; t += 2) {
        RD_A(0, 0); RD_B2(0, 0);
        STAGE_A(1, 0, t + 1);
        WAITLG8();
        BAR(); WAITLG0(); SB();
        QUAD(0, 0);
        BAR();
        RD_B2(0, 1);
        STAGE_A(1, 1, t + 1);
        BAR(); WAITLG0(); SB();
        QUAD(0, 1);
        BAR();
        RD_A(0, 1);
        if (t + 2 < KT) STAGE_B(0, 0, t + 2);
        BAR(); WAITLG0(); SB();
        QUAD(1, 1);
        BAR();
        if (t + 2 < KT) { STAGE_B(0, 1, t + 2); WAITVM4(); } else { WAITVM0(); }
        BAR(); WAITLG0(); SB();
        QUAD(1, 0);
        BAR();
        RD_A(1, 0); RD_B2(1, 0);
        if (t + 2 < KT) STAGE_A(0, 0, t + 2);
        WAITLG8();
        BAR(); WAITLG0(); SB();
        QUAD(0, 0);
        BAR();
        RD_B2(1, 1);
        if (t + 2 < KT) STAGE_A(0, 1, t + 2);
        BAR(); WAITLG0(); SB();
        QUAD(0, 1);
        BAR();
        RD_A(1, 1);
        if (t + 3 < KT) STAGE_B(1, 0, t + 3);
        BAR(); WAITLG0(); SB();
        QUAD(1, 1);
        BAR();
        if (t + 3 < KT) { STAGE_B(1, 1, t + 3); WAITVM4(); } else { WAITVM0(); }
        BAR(); WAITLG0(); SB();
        QUAD(1, 0);
        BAR();
    }

    #pragma unroll
    for (int m = 0; m < 8; m++)
        #pragma unroll
        for (int n = 0; n < 4; n++)
            #pragma unroll
            for (int j = 0; j < 4; j++) {
                int row = brow + wr * 128 + m * 16 + g4 * 4 + j;
                int col = bcol + wc * 64 + n * 16 + r;
                float v = acc[m][n][j];
                if (EP == 0) {
                    outb[(size_t)row * N + col] = f2bf(v);
                } else if (EP == 1) {
                    outf[(size_t)row * N + col] = v + bias[col] + res[(size_t)row * N + col];
                } else {
                    outb[(size_t)row * N + col] = f2bf(fmaxf(v + bias[col], 0.f));
                }
            }
}

// ---------------- Flash attention: 8 waves, 2 q-tiles share staged K/V ----------------
__global__ __launch_bounds__(512, 4) void attn_kernel(
    const unsigned short* __restrict__ qkv, unsigned short* __restrict__ att)
{
    __shared__ __align__(16) unsigned short Ks[2][64 * 64];
    __shared__ __align__(16) unsigned short Vt[2][64 * 66];
    __shared__ __align__(16) unsigned short Ps[2][64 * 64];
    int tid = threadIdx.x, lane = tid & 63, w = tid >> 6;
    int half = w >> 2;
    int pi = blockIdx.x;                       // 0..3
    int bh = blockIdx.y, bb = bh >> 4, hh = bh & 15;
    int r = lane & 15, g4 = lane >> 4;
    const unsigned short* base = qkv + (size_t)bb * 1024 * 3072;
    const float SCL = 0.03125f * 1.4426950408889634f;
    int vd = tid & 63, vsb = tid >> 6;
    int prow = (w & 3) * 16 + r;
    int pswz = (r & 7) << 3;

    for (int sidx = 0; sidx < 2; sidx++) {
        int s = sidx ? (7 - pi) : pi;
        int qt = 2 * s + half;
        int qtmax = 2 * s + 1;
        int qrow = qt * 64 + prow;

        bf16x8 qf[2];
        #pragma unroll
        for (int kk = 0; kk < 2; kk++)
            qf[kk] = *(const bf16x8*)&base[(size_t)qrow * 3072 + hh * 64 + kk * 32 + g4 * 8];

        f32x4 oacc[4];
        #pragma unroll
        for (int i = 0; i < 4; i++) oacc[i] = (f32x4){0.f, 0.f, 0.f, 0.f};
        float m_i = -INFINITY, l_i = 0.f;

        unsigned short vtmp[8];
        {
            int row = tid >> 3, slot = tid & 7;
            int gs = slot ^ (row & 7);
            gload16(base + (size_t)row * 3072 + 1024 + hh * 64 + gs * 8, &Ks[0][tid * 8]);
            #pragma unroll
            for (int i2 = 0; i2 < 8; i2++)
                vtmp[i2] = base[(size_t)(vsb * 8 + i2) * 3072 + 2048 + hh * 64 + vd];
            union { unsigned short u[8]; bf16x8 v; } w0;
            #pragma unroll
            for (int i2 = 0; i2 < 8; i2++) w0.u[i2] = vtmp[i2];
            *(bf16x8*)&Vt[0][vd * 66 + (vsb ^ (vd & 7)) * 8] = w0.v;
        }
        __syncthreads();

        for (int ki = 0; ki <= qtmax; ki++) {
            int cur = ki & 1;
            bool pre = (ki < qtmax);
            bool act = (ki <= qt);
            if (pre) {
                int k1 = (ki + 1) * 64;
                int row = tid >> 3, slot = tid & 7;
                int gs = slot ^ (row & 7);
                gload16(base + (size_t)(k1 + row) * 3072 + 1024 + hh * 64 + gs * 8, &Ks[cur ^ 1][tid * 8]);
                #pragma unroll
                for (int i2 = 0; i2 < 8; i2++)
                    vtmp[i2] = base[(size_t)(k1 + vsb * 8 + i2) * 3072 + 2048 + hh * 64 + vd];
            }

            if (act) {
                int k0 = ki * 64;
                f32x4 sacc[4];
                #pragma unroll
                for (int c4 = 0; c4 < 4; c4++) sacc[c4] = (f32x4){0.f, 0.f, 0.f, 0.f};
                #pragma unroll
                for (int c4 = 0; c4 < 4; c4++) {
                    int krow = c4 * 16 + r;
                    #pragma unroll
                    for (int kk = 0; kk < 2; kk++) {
                        int slot = (g4 + kk * 4) ^ (krow & 7);
                        bf16x8 kf = *(const bf16x8*)&Ks[cur][krow * 64 + slot * 8];
                        sacc[c4] = __builtin_amdgcn_mfma_f32_16x16x32_bf16(kf, qf[kk], sacc[c4], 0, 0, 0);
                    }
                }
                bool diag = (ki == qt);
                float sv[4][4];
                float smax = -INFINITY;
                #pragma unroll
                for (int c4 = 0; c4 < 4; c4++)
                    #pragma unroll
                    for (int i = 0; i < 4; i++) {
                        float sa = sacc[c4][i];
                        if (diag && (k0 + c4 * 16 + g4 * 4 + i) > qrow) sa = -INFINITY;
                        sv[c4][i] = sa;
                        smax = fmaxf(smax, sa);
                    }
                smax = fmaxf(smax, __shfl_xor(smax, 16));
                smax = fmaxf(smax, __shfl_xor(smax, 32));
                if (!__all((smax - m_i) * SCL <= 8.f)) {
                    float mn = fmaxf(m_i, smax);
                    float fs = exp2f((m_i - mn) * SCL);
                    m_i = mn;
                    l_i *= fs;
                    #pragma unroll
                    for (int n4 = 0; n4 < 4; n4++)
                        #pragma unroll
                        for (int i = 0; i < 4; i++) oacc[n4][i] *= fs;
                }
                float nb = -m_i * SCL;
                float rsum = 0.f;
                float pv[4][4];
                #pragma unroll
                for (int c4 = 0; c4 < 4; c4++)
                    #pragma unroll
                    for (int i = 0; i < 4; i++) {
                        float p = exp2f(fmaf(sv[c4][i], SCL, nb));
                        pv[c4][i] = p;
                        rsum += p;
                    }
                rsum += __shfl_xor(rsum, 16);
                rsum += __shfl_xor(rsum, 32);
                l_i += rsum;
                #pragma unroll
                for (int c4 = 0; c4 < 4; c4++) {
                    unsigned long long ll = (unsigned long long)cvtpk(pv[c4][0], pv[c4][1])
                                          | ((unsigned long long)cvtpk(pv[c4][2], pv[c4][3]) << 32);
                    *(unsigned long long*)&Ps[half][(prow * 64 + c4 * 16 + g4 * 4) ^ pswz] = ll;
                }
                WAITLG0();
            }
            if (pre) {
                union { unsigned short u[8]; bf16x8 v; } w0;
                #pragma unroll
                for (int i2 = 0; i2 < 8; i2++) w0.u[i2] = vtmp[i2];
                *(bf16x8*)&Vt[cur ^ 1][vd * 66 + (vsb ^ (vd & 7)) * 8] = w0.v;
            }
            if (act) {
                bf16x8 pa[2];
                #pragma unroll
                for (int kk = 0; kk < 2; kk++)
                    pa[kk] = *(const bf16x8*)&Ps[half][(prow * 64 + kk * 32 + g4 * 8) ^ pswz];
                #pragma unroll
                for (int n4 = 0; n4 < 4; n4++) {
                    int d = n4 * 16 + r;
                    #pragma unroll
                    for (int kk = 0; kk < 2; kk++) {
                        bf16x8 vf = *(const bf16x8*)&Vt[cur][d * 66 + (((kk * 4 + g4) ^ (d & 7)) << 3)];
                        oacc[n4] = __builtin_amdgcn_mfma_f32_16x16x32_bf16(vf, pa[kk], oacc[n4], 0, 0, 0);
                    }
                }
            }
            __syncthreads();
        }

        float inv = 1.f / l_i;
        #pragma unroll
        for (int n4 = 0; n4 < 4; n4++) {
            unsigned long long ll = (unsigned long long)cvtpk(oacc[n4][0] * inv, oacc[n4][1] * inv)
                                  | ((unsigned long long)cvtpk(oacc[n4][2] * inv, oacc[n4][3] * inv) << 32);
            size_t oidx = ((size_t)(bb * 1024 + qrow)) * 1024 + hh * 64 + n4 * 16 + g4 * 4;
            *(unsigned long long*)&att[oidx] = ll;
        }
    }
}

// ---------------- host ----------------
extern "C" void kernel_launch(void* const* d_in, const int* in_sizes, int n_in,
                              void* d_out, int out_size, void* d_ws, size_t ws_size,
                              hipStream_t stream)
{
    const float* x     = (const float*)d_in[0];
    const float* Wq    = (const float*)d_in[1];
    const float* Wk    = (const float*)d_in[2];
    const float* Wv    = (const float*)d_in[3];
    const float* eq    = (const float*)d_in[4];
    const float* bq    = (const float*)d_in[5];
    const float* ek    = (const float*)d_in[6];
    const float* bk    = (const float*)d_in[7];
    const float* ev    = (const float*)d_in[8];
    const float* bv    = (const float*)d_in[9];
    const float* Wp    = (const float*)d_in[10];
    const float* ep    = (const float*)d_in[11];
    const float* bp    = (const float*)d_in[12];
    const float* biasp = (const float*)d_in[13];
    const float* W1    = (const float*)d_in[14];
    const float* e1    = (const float*)d_in[15];
    const float* b1    = (const float*)d_in[16];
    const float* bias1 = (const float*)d_in[17];
    const float* W2    = (const float*)d_in[18];
    const float* e2    = (const float*)d_in[19];
    const float* b2    = (const float*)d_in[20];
    const float* bias2 = (const float*)d_in[21];
    const float* g1    = (const float*)d_in[22];
    const float* be1   = (const float*)d_in[23];
    const float* g2    = (const float*)d_in[24];
    const float* be2   = (const float*)d_in[25];

    const size_t MB = 1ull << 20;
    char* ws = (char*)d_ws;
    unsigned short* Wqkvq = (unsigned short*)(ws);            //  6 MB
    unsigned short* Wpq   = (unsigned short*)(ws + 6 * MB);   //  2 MB
    unsigned short* W1q   = (unsigned short*)(ws + 8 * MB);   //  8 MB
    unsigned short* W2q   = (unsigned short*)(ws + 16 * MB);  //  8 MB
    unsigned short* hbuf  = (unsigned short*)(ws + 24 * MB);  // 16 MB
    unsigned short* qkvb  = (unsigned short*)(ws + 40 * MB);  // 48 MB; later f (64 MB)
    unsigned short* fbuf  = qkvb;
    unsigned short* attb  = (unsigned short*)(ws + 88 * MB);  // 16 MB
    unsigned short* x2b   = (unsigned short*)(ws + 104 * MB); // 16 MB (bf16 residual)

    // fused: 6 weight fake-quants (blocks 0-2047) + LN1 (blocks 2048-4095)
    fused_pre_kernel<<<4096, 256, 0, stream>>>(Wq, Wk, Wv, Wp, W1, W2,
                                               eq, ek, ev, ep, e1, e2,
                                               bq, bk, bv, bp, b1, b2,
                                               Wqkvq, Wpq, W1q, W2q,
                                               x, g1, be1, hbuf);

    // QKV: [8192,3072] bf16, 256^2 8-phase
    gemm256<0><<<dim3(12, 32), 512, 0, stream>>>(hbuf, Wqkvq, 3072, 1024, nullptr, nullptr, nullptr, qkvb);
    // attention (8-wave shared staging, supertile-paired)
    attn_kernel<<<dim3(4, 128), 512, 0, stream>>>(qkvb, attb);
    // proj + bias + residual(x fp32) -> x2b (bf16)
    gemm_bt<3><<<dim3(8, 64), 256, 0, stream>>>(attb, Wpq, 1024, 1024, biasp, x, nullptr, nullptr, x2b);
    // LN2: x2b (bf16) -> hbuf
    ln_bf_kernel<<<2048, 256, 0, stream>>>(x2b, g2, be2, hbuf);
    // FFN1: relu(h2 W1^T + b1) -> f (bf16), 256^2 8-phase
    gemm256<2><<<dim3(16, 32), 512, 0, stream>>>(hbuf, W1q, 4096, 1024, bias1, nullptr, nullptr, fbuf);
    // FFN2: f W2^T + b2 + x2b(bf16) -> out (fp32)
    gemm_bt<4><<<dim3(8, 64), 256, 0, stream>>>(fbuf, W2q, 1024, 4096, bias2, nullptr, x2b, (float*)d_out, nullptr);
}

// Round 9
// 318.987 us; speedup vs baseline: 1.5758x; 1.0104x over previous
//
#include <hip/hip_runtime.h>
#include <hip/hip_bf16.h>
#include <math.h>

#define DEVI __device__ __forceinline__

typedef __attribute__((ext_vector_type(8))) short bf16x8;
typedef __attribute__((ext_vector_type(4))) float f32x4;

DEVI unsigned short f2bf(float f) {
    union { float f; unsigned u; } v; v.f = f;
    unsigned r = v.u + 0x7FFFu + ((v.u >> 16) & 1u);
    return (unsigned short)(r >> 16);
}

DEVI float bf2f(unsigned short u) {
    union { unsigned u; float f; } v; v.u = (unsigned)u << 16; return v.f;
}

DEVI unsigned cvtpk(float lo, float hi) {   // D = bf16(hi)<<16 | bf16(lo), RNE
    unsigned d;
    asm volatile("v_cvt_pk_bf16_f32 %0, %1, %2" : "=v"(d) : "v"(lo), "v"(hi));
    return d;
}

DEVI void gload16(const void* g, void* l) {
    __builtin_amdgcn_global_load_lds((const __attribute__((address_space(1))) void*)g,
                                     (__attribute__((address_space(3))) void*)l, 16, 0, 0);
}

#define WAITVM4() asm volatile("s_waitcnt vmcnt(4)" ::: "memory")
#define WAITVM0() asm volatile("s_waitcnt vmcnt(0)" ::: "memory")
#define WAITLG0() asm volatile("s_waitcnt lgkmcnt(0)" ::: "memory")
#define WAITLG8() asm volatile("s_waitcnt lgkmcnt(8)" ::: "memory")
#define BAR()     __builtin_amdgcn_s_barrier()
#define SB()      __builtin_amdgcn_sched_barrier(0)

// ---------------- fused pre-pass: 6 weight fake-quants + LN1, one dispatch ----------------
__global__ __launch_bounds__(256) void fused_pre_kernel(
    const float* __restrict__ Wq, const float* __restrict__ Wk, const float* __restrict__ Wv,
    const float* __restrict__ Wp, const float* __restrict__ W1, const float* __restrict__ W2,
    const float* __restrict__ eq, const float* __restrict__ ek, const float* __restrict__ ev,
    const float* __restrict__ ep, const float* __restrict__ e1, const float* __restrict__ e2,
    const float* __restrict__ bq, const float* __restrict__ bk, const float* __restrict__ bv,
    const float* __restrict__ bp, const float* __restrict__ b1, const float* __restrict__ b2,
    unsigned short* __restrict__ Wqkvq, unsigned short* __restrict__ Wpq,
    unsigned short* __restrict__ W1q, unsigned short* __restrict__ W2q,
    const float* __restrict__ x, const float* __restrict__ g1, const float* __restrict__ be1,
    unsigned short* __restrict__ hbuf)
{
    const int M1 = 1 << 20;
    if (blockIdx.x < 2048) {
        const int NCH = 3 * M1;
        const int STRIDE = 2048 * 256;
        for (int c = blockIdx.x * blockDim.x + threadIdx.x; c < NCH; c += STRIDE) {
            int elem = c * 4;
            const float *W, *e, *b; unsigned short* o; int lgK, local;
            if (elem < M1)            { W = Wq; e = eq; b = bq; o = Wqkvq;          lgK = 10; local = elem; }
            else if (elem < 2 * M1)   { W = Wk; e = ek; b = bk; o = Wqkvq + M1;     lgK = 10; local = elem - M1; }
            else if (elem < 3 * M1)   { W = Wv; e = ev; b = bv; o = Wqkvq + 2 * M1; lgK = 10; local = elem - 2 * M1; }
            else if (elem < 4 * M1)   { W = Wp; e = ep; b = bp; o = Wpq;            lgK = 10; local = elem - 3 * M1; }
            else if (elem < 8 * M1)   { W = W1; e = e1; b = b1; o = W1q;            lgK = 10; local = elem - 4 * M1; }
            else                      { W = W2; e = e2; b = b2; o = W2q;            lgK = 12; local = elem - 8 * M1; }
            int row = local >> lgK;
            float evv = e[row], bvv = b[row];
            float br = fmaxf(bvv, 0.f);
            float mn, mx;
            if (br > 0.f) { float p = exp2f(br - 1.f); mn = -p; mx = p - 1.f; }
            else          { mn = 0.f; mx = 0.f; }
            float si = exp2f(-evv), so = exp2f(evv);
            union { float4 v4; float a[4]; } v;
            v.v4 = *(const float4*)(W + local);
            union { unsigned short u[4]; unsigned long long ll; } ot;
            #pragma unroll
            for (int j = 0; j < 4; j++) {
                float qw = fminf(fmaxf(si * v.a[j], mn), mx);
                ot.u[j] = f2bf(so * rintf(qw));
            }
            *(unsigned long long*)(o + local) = ot.ll;
        }
    } else {
        int row = (blockIdx.x - 2048) * 4 + (threadIdx.x >> 6);
        int lane = threadIdx.x & 63;
        const float* xp = x + (size_t)row * 1024 + lane * 16;
        float a[16];
        #pragma unroll
        for (int j = 0; j < 4; j++) {
            float4 v = *(const float4*)(xp + j * 4);
            a[j * 4] = v.x; a[j * 4 + 1] = v.y; a[j * 4 + 2] = v.z; a[j * 4 + 3] = v.w;
        }
        float s = 0.f, s2 = 0.f;
        #pragma unroll
        for (int i = 0; i < 16; i++) { s += a[i]; s2 += a[i] * a[i]; }
        #pragma unroll
        for (int off = 1; off < 64; off <<= 1) { s += __shfl_xor(s, off); s2 += __shfl_xor(s2, off); }
        float mu = s * (1.0f / 1024.0f);
        float var = s2 * (1.0f / 1024.0f) - mu * mu;
        float rs = rsqrtf(var + 1e-5f);
        int c0 = lane * 16;
        float r[16];
        #pragma unroll
        for (int i = 0; i < 16; i++) r[i] = (a[i] - mu) * rs * g1[c0 + i] + be1[c0 + i];
        unsigned w[8];
        #pragma unroll
        for (int j = 0; j < 8; j++) w[j] = cvtpk(r[2 * j], r[2 * j + 1]);
        unsigned short* op = hbuf + (size_t)row * 1024 + c0;
        *(uint4*)(op)     = *(uint4*)&w[0];
        *(uint4*)(op + 8) = *(uint4*)&w[4];
    }
}

// ---------------- LayerNorm wave-per-row, bf16 in -> bf16 out (LN2) ----------------
__global__ __launch_bounds__(256) void ln_bf_kernel(
    const unsigned short* __restrict__ xb, const float* __restrict__ g, const float* __restrict__ be,
    unsigned short* __restrict__ out)
{
    int row = blockIdx.x * 4 + (threadIdx.x >> 6);
    int lane = threadIdx.x & 63;
    const unsigned short* xp = xb + (size_t)row * 1024 + lane * 16;
    float a[16];
    #pragma unroll
    for (int j = 0; j < 2; j++) {
        bf16x8 v = *(const bf16x8*)(xp + j * 8);
        #pragma unroll
        for (int i = 0; i < 8; i++) a[j * 8 + i] = bf2f(((unsigned short*)&v)[i]);
    }
    float s = 0.f, s2 = 0.f;
    #pragma unroll
    for (int i = 0; i < 16; i++) { s += a[i]; s2 += a[i] * a[i]; }
    #pragma unroll
    for (int off = 1; off < 64; off <<= 1) { s += __shfl_xor(s, off); s2 += __shfl_xor(s2, off); }
    float mu = s * (1.0f / 1024.0f);
    float var = s2 * (1.0f / 1024.0f) - mu * mu;
    float rs = rsqrtf(var + 1e-5f);
    int c0 = lane * 16;
    float r[16];
    #pragma unroll
    for (int i = 0; i < 16; i++) r[i] = (a[i] - mu) * rs * g[c0 + i] + be[c0 + i];
    unsigned w[8];
    #pragma unroll
    for (int j = 0; j < 8; j++) w[j] = cvtpk(r[2 * j], r[2 * j + 1]);
    unsigned short* op = out + (size_t)row * 1024 + c0;
    *(uint4*)(op)     = *(uint4*)&w[0];
    *(uint4*)(op + 8) = *(uint4*)&w[4];
}

// ---------------- GEMM 128x128, BK=64, 8 waves (64x32 wave-tile), counted-vmcnt 2-phase ----
// Ledger: iter t issues 4 loads (stage t+1) -> outstanding 8; WAITVM4 drains the oldest 4
// (= tile t's stage) -> BAR1 -> all waves see buf[cur] complete -> MFMA (compiler lgkm waits)
// -> BAR2 -> safe to overwrite buf[cur^1]'s partner next iter. Tail drains vmcnt(0).
// EP 0: bf16. EP 1: f32=acc+bias+res(f32). EP 2: bf16 relu(acc+bias).
// EP 3: bf16=acc+bias+res(f32). EP 4: f32=acc+bias+resb(bf16).
#define GSTAGE(buf, kt) do { \
    _Pragma("unroll") for (int q_ = 0; q_ < 2; q_++) { \
        int idx_ = q_ * 512 + tid; int row_ = idx_ >> 3; int gs_ = (idx_ & 7) ^ (row_ & 7); \
        gload16(A  + (size_t)(brow + row_) * K + (kt) * 64 + gs_ * 8, &As[buf][idx_ * 8]); \
        gload16(Bw + (size_t)(bcol + row_) * K + (kt) * 64 + gs_ * 8, &Bs[buf][idx_ * 8]); \
    } } while (0)

template<int EP>
__global__ __launch_bounds__(512, 2) void gemm_bt(
    const unsigned short* __restrict__ A, const unsigned short* __restrict__ Bw,
    int N, int K,
    const float* __restrict__ bias, const float* __restrict__ res,
    const unsigned short* __restrict__ resb,
    float* __restrict__ outf, unsigned short* __restrict__ outb)
{
    __shared__ __align__(16) unsigned short As[2][128 * 64];
    __shared__ __align__(16) unsigned short Bs[2][128 * 64];
    int tid = threadIdx.x, lane = tid & 63, wave = tid >> 6;
    int gx = gridDim.x;
    int nwg = gx * gridDim.y;
    int id = blockIdx.y * gx + blockIdx.x;
    int swz = (id & 7) * (nwg >> 3) + (id >> 3);
    int brow = (swz / gx) * 128, bcol = (swz % gx) * 128;
    int wr = wave >> 2, wc = wave & 3;       // 2 M-waves x 4 N-waves; wave tile 64x32
    int r = lane & 15, g4 = lane >> 4;
    f32x4 acc[4][2];
    #pragma unroll
    for (int i = 0; i < 4; i++)
        #pragma unroll
        for (int j = 0; j < 2; j++) acc[i][j] = (f32x4){0.f, 0.f, 0.f, 0.f};

    int nt = K >> 6;
    GSTAGE(0, 0);
    __syncthreads();
    int cur = 0;
    for (int t = 0; t < nt; ++t) {
        if (t + 1 < nt) { GSTAGE(cur ^ 1, t + 1); WAITVM4(); }
        else            { WAITVM0(); }
        __builtin_amdgcn_s_barrier();
        #pragma unroll
        for (int kk = 0; kk < 2; kk++) {
            bf16x8 af[4], bfr[2];
            #pragma unroll
            for (int mi = 0; mi < 4; mi++) {
                int rh = wr * 64 + mi * 16 + r;
                af[mi] = *(const bf16x8*)&As[cur][rh * 64 + (((kk * 4 + g4) ^ (rh & 7)) << 3)];
            }
            #pragma unroll
            for (int ni = 0; ni < 2; ni++) {
                int rh = wc * 32 + ni * 16 + r;
                bfr[ni] = *(const bf16x8*)&Bs[cur][rh * 64 + (((kk * 4 + g4) ^ (rh & 7)) << 3)];
            }
            #pragma unroll
            for (int mi = 0; mi < 4; mi++)
                #pragma unroll
                for (int ni = 0; ni < 2; ni++)
                    acc[mi][ni] = __builtin_amdgcn_mfma_f32_16x16x32_bf16(af[mi], bfr[ni], acc[mi][ni], 0, 0, 0);
        }
        __builtin_amdgcn_s_barrier();
        cur ^= 1;
    }

    #pragma unroll
    for (int mi = 0; mi < 4; mi++)
        #pragma unroll
        for (int ni = 0; ni < 2; ni++)
            #pragma unroll
            for (int i = 0; i < 4; i++) {
                int row = brow + wr * 64 + mi * 16 + g4 * 4 + i;
                int col = bcol + wc * 32 + ni * 16 + r;
                float v = acc[mi][ni][i];
                if (EP == 0) {
                    outb[(size_t)row * N + col] = f2bf(v);
                } else if (EP == 1) {
                    outf[(size_t)row * N + col] = v + bias[col] + res[(size_t)row * N + col];
                } else if (EP == 2) {
                    outb[(size_t)row * N + col] = f2bf(fmaxf(v + bias[col], 0.f));
                } else if (EP == 3) {
                    outb[(size_t)row * N + col] = f2bf(v + bias[col] + res[(size_t)row * N + col]);
                } else {
                    outf[(size_t)row * N + col] = v + bias[col] + bf2f(resb[(size_t)row * N + col]);
                }
            }
}

// ---------------- GEMM 256x256 8-phase (ledger-verified; clean r6/r7/r8) ----------------
#define STAGE_A(b, h, kt) do { \
    _Pragma("unroll") \
    for (int ld = 0; ld < 2; ld++) { \
        int idx = ld * 512 + tid; int rw = idx >> 3; int gs = (idx & 7) ^ (rw & 7); \
        gload16(Aa + (size_t)(brow + (h) * 128 + rw) * K + (kt) * 64 + gs * 8, &As[b][h][idx * 8]); \
    } } while (0)

#define STAGE_B(b, h, kt) do { \
    _Pragma("unroll") \
    for (int ld = 0; ld < 2; ld++) { \
        int idx = ld * 512 + tid; int rw = idx >> 3; int gs = (idx & 7) ^ (rw & 7); \
        gload16(Bw + (size_t)(bcol + (h) * 128 + rw) * K + (kt) * 64 + gs * 8, &Bs[b][h][idx * 8]); \
    } } while (0)

#define RD_A(b, mh) do { \
    _Pragma("unroll") for (int mi = 0; mi < 4; mi++) \
    _Pragma("unroll") for (int kk = 0; kk < 2; kk++) { \
        int rh = (mh) * 64 + mi * 16 + r; \
        af[mi][kk] = *(const bf16x8*)&As[b][wr][rh * 64 + (((kk * 4 + g4) ^ (rh & 7)) << 3)]; \
    } } while (0)

#define RD_B2(b, nh) do { \
    _Pragma("unroll") for (int nj = 0; nj < 2; nj++) \
    _Pragma("unroll") for (int kk = 0; kk < 2; kk++) { \
        int rh = (wc & 1) * 64 + ((nh) * 2 + nj) * 16 + r; \
        bfr[(nh) * 2 + nj][kk] = *(const bf16x8*)&Bs[b][wc >> 1][rh * 64 + (((kk * 4 + g4) ^ (rh & 7)) << 3)]; \
    } } while (0)

#define QUAD(mh, nh) do { \
    __builtin_amdgcn_s_setprio(1); \
    _Pragma("unroll") for (int mi = 0; mi < 4; mi++) \
    _Pragma("unroll") for (int nj = 0; nj < 2; nj++) \
    _Pragma("unroll") for (int kk = 0; kk < 2; kk++) \
        acc[(mh) * 4 + mi][(nh) * 2 + nj] = __builtin_amdgcn_mfma_f32_16x16x32_bf16( \
            af[mi][kk], bfr[(nh) * 2 + nj][kk], acc[(mh) * 4 + mi][(nh) * 2 + nj], 0, 0, 0); \
    __builtin_amdgcn_s_setprio(0); \
    } while (0)

template<int EP>
__global__ __launch_bounds__(512, 2) void gemm256(
    const unsigned short* __restrict__ Aa, const unsigned short* __restrict__ Bw,
    int N, int K,
    const float* __restrict__ bias, const float* __restrict__ res,
    float* __restrict__ outf, unsigned short* __restrict__ outb)
{
    __shared__ __align__(16) unsigned short As[2][2][128 * 64];
    __shared__ __align__(16) unsigned short Bs[2][2][128 * 64];
    int tid = threadIdx.x, lane = tid & 63, wave = tid >> 6;
    int gx = gridDim.x;
    int nwg = gx * gridDim.y;
    int id = blockIdx.y * gx + blockIdx.x;
    int swz = (id & 7) * (nwg >> 3) + (id >> 3);
    int brow = (swz / gx) * 256, bcol = (swz % gx) * 256;
    int wr = wave >> 2, wc = wave & 3;
    int r = lane & 15, g4 = lane >> 4;
    int KT = K >> 6;

    f32x4 acc[8][4];
    #pragma unroll
    for (int i = 0; i < 8; i++)
        #pragma unroll
        for (int j = 0; j < 4; j++) acc[i][j] = (f32x4){0.f, 0.f, 0.f, 0.f};
    bf16x8 af[4][2], bfr[4][2];

    STAGE_A(0, 0, 0); STAGE_A(0, 1, 0); STAGE_B(0, 0, 0); STAGE_B(0, 1, 0);
    STAGE_B(1, 0, 1); STAGE_B(1, 1, 1);
    WAITVM4();
    BAR();

    for (int t = 0; t < KT; t += 2) {
        RD_A(0, 0); RD_B2(0, 0);
        STAGE_A(1, 0, t + 1);
        WAITLG8();
        BAR(); WAITLG0(); SB();
        QUAD(0, 0);
        BAR();
        RD_B2(0, 1);
        STAGE_A(1, 1, t + 1);
        BAR(); WAITLG0(); SB();
        QUAD(0, 1);
        BAR();
        RD_A(0, 1);
        if (t + 2 < KT) STAGE_B(0, 0, t + 2);
        BAR(); WAITLG0(); SB();
        QUAD(1, 1);
        BAR();
        if (t + 2 < KT) { STAGE_B(0, 1, t + 2); WAITVM4(); } else { WAITVM0(); }
        BAR(); WAITLG0(); SB();
        QUAD(1, 0);
        BAR();
        RD_A(1, 0); RD_B2(1, 0);
        if (t + 2 < KT) STAGE_A(0, 0, t + 2);
        WAITLG8();
        BAR(); WAITLG0(); SB();
        QUAD(0, 0);
        BAR();
        RD_B2(1, 1);
        if (t + 2 < KT) STAGE_A(0, 1, t + 2);
        BAR(); WAITLG0(); SB();
        QUAD(0, 1);
        BAR();
        RD_A(1, 1);
        if (t + 3 < KT) STAGE_B(1, 0, t + 3);
        BAR(); WAITLG0(); SB();
        QUAD(1, 1);
        BAR();
        if (t + 3 < KT) { STAGE_B(1, 1, t + 3); WAITVM4(); } else { WAITVM0(); }
        BAR(); WAITLG0(); SB();
        QUAD(1, 0);
        BAR();
    }

    #pragma unroll
    for (int m = 0; m < 8; m++)
        #pragma unroll
        for (int n = 0; n < 4; n++)
            #pragma unroll
            for (int j = 0; j < 4; j++) {
                int row = brow + wr * 128 + m * 16 + g4 * 4 + j;
                int col = bcol + wc * 64 + n * 16 + r;
                float v = acc[m][n][j];
                if (EP == 0) {
                    outb[(size_t)row * N + col] = f2bf(v);
                } else if (EP == 1) {
                    outf[(size_t)row * N + col] = v + bias[col] + res[(size_t)row * N + col];
                } else {
                    outb[(size_t)row * N + col] = f2bf(fmaxf(v + bias[col], 0.f));
                }
            }
}

// ---------------- Flash attention: 8 waves, 2 q-tiles share staged K/V ----------------
__global__ __launch_bounds__(512, 4) void attn_kernel(
    const unsigned short* __restrict__ qkv, unsigned short* __restrict__ att)
{
    __shared__ __align__(16) unsigned short Ks[2][64 * 64];
    __shared__ __align__(16) unsigned short Vt[2][64 * 66];
    __shared__ __align__(16) unsigned short Ps[2][64 * 64];
    int tid = threadIdx.x, lane = tid & 63, w = tid >> 6;
    int half = w >> 2;
    int pi = blockIdx.x;                       // 0..3
    int bh = blockIdx.y, bb = bh >> 4, hh = bh & 15;
    int r = lane & 15, g4 = lane >> 4;
    const unsigned short* base = qkv + (size_t)bb * 1024 * 3072;
    const float SCL = 0.03125f * 1.4426950408889634f;
    int vd = tid & 63, vsb = tid >> 6;
    int prow = (w & 3) * 16 + r;
    int pswz = (r & 7) << 3;

    for (int sidx = 0; sidx < 2; sidx++) {
        int s = sidx ? (7 - pi) : pi;
        int qt = 2 * s + half;
        int qtmax = 2 * s + 1;
        int qrow = qt * 64 + prow;

        bf16x8 qf[2];
        #pragma unroll
        for (int kk = 0; kk < 2; kk++)
            qf[kk] = *(const bf16x8*)&base[(size_t)qrow * 3072 + hh * 64 + kk * 32 + g4 * 8];

        f32x4 oacc[4];
        #pragma unroll
        for (int i = 0; i < 4; i++) oacc[i] = (f32x4){0.f, 0.f, 0.f, 0.f};
        float m_i = -INFINITY, l_i = 0.f;

        unsigned short vtmp[8];
        {
            int row = tid >> 3, slot = tid & 7;
            int gs = slot ^ (row & 7);
            gload16(base + (size_t)row * 3072 + 1024 + hh * 64 + gs * 8, &Ks[0][tid * 8]);
            #pragma unroll
            for (int i2 = 0; i2 < 8; i2++)
                vtmp[i2] = base[(size_t)(vsb * 8 + i2) * 3072 + 2048 + hh * 64 + vd];
            union { unsigned short u[8]; bf16x8 v; } w0;
            #pragma unroll
            for (int i2 = 0; i2 < 8; i2++) w0.u[i2] = vtmp[i2];
            *(bf16x8*)&Vt[0][vd * 66 + (vsb ^ (vd & 7)) * 8] = w0.v;
        }
        __syncthreads();

        for (int ki = 0; ki <= qtmax; ki++) {
            int cur = ki & 1;
            bool pre = (ki < qtmax);
            bool act = (ki <= qt);
            if (pre) {
                int k1 = (ki + 1) * 64;
                int row = tid >> 3, slot = tid & 7;
                int gs = slot ^ (row & 7);
                gload16(base + (size_t)(k1 + row) * 3072 + 1024 + hh * 64 + gs * 8, &Ks[cur ^ 1][tid * 8]);
                #pragma unroll
                for (int i2 = 0; i2 < 8; i2++)
                    vtmp[i2] = base[(size_t)(k1 + vsb * 8 + i2) * 3072 + 2048 + hh * 64 + vd];
            }

            if (act) {
                int k0 = ki * 64;
                f32x4 sacc[4];
                #pragma unroll
                for (int c4 = 0; c4 < 4; c4++) sacc[c4] = (f32x4){0.f, 0.f, 0.f, 0.f};
                #pragma unroll
                for (int c4 = 0; c4 < 4; c4++) {
                    int krow = c4 * 16 + r;
                    #pragma unroll
                    for (int kk = 0; kk < 2; kk++) {
                        int slot = (g4 + kk * 4) ^ (krow & 7);
                        bf16x8 kf = *(const bf16x8*)&Ks[cur][krow * 64 + slot * 8];
                        sacc[c4] = __builtin_amdgcn_mfma_f32_16x16x32_bf16(kf, qf[kk], sacc[c4], 0, 0, 0);
                    }
                }
                bool diag = (ki == qt);
                float sv[4][4];
                float smax = -INFINITY;
                #pragma unroll
                for (int c4 = 0; c4 < 4; c4++)
                    #pragma unroll
                    for (int i = 0; i < 4; i++) {
                        float sa = sacc[c4][i];
                        if (diag && (k0 + c4 * 16 + g4 * 4 + i) > qrow) sa = -INFINITY;
                        sv[c4][i] = sa;
                        smax = fmaxf(smax, sa);
                    }
                smax = fmaxf(smax, __shfl_xor(smax, 16));
                smax = fmaxf(smax, __shfl_xor(smax, 32));
                if (!__all((smax - m_i) * SCL <= 8.f)) {
                    float mn = fmaxf(m_i, smax);
                    float fs = exp2f((m_i - mn) * SCL);
                    m_i = mn;
                    l_i *= fs;
                    #pragma unroll
                    for (int n4 = 0; n4 < 4; n4++)
                        #pragma unroll
                        for (int i = 0; i < 4; i++) oacc[n4][i] *= fs;
                }
                float nb = -m_i * SCL;
                float rsum = 0.f;
                float pv[4][4];
                #pragma unroll
                for (int c4 = 0; c4 < 4; c4++)
                    #pragma unroll
                    for (int i = 0; i < 4; i++) {
                        float p = exp2f(fmaf(sv[c4][i], SCL, nb));
                        pv[c4][i] = p;
                        rsum += p;
                    }
                rsum += __shfl_xor(rsum, 16);
                rsum += __shfl_xor(rsum, 32);
                l_i += rsum;
                #pragma unroll
                for (int c4 = 0; c4 < 4; c4++) {
                    unsigned long long ll = (unsigned long long)cvtpk(pv[c4][0], pv[c4][1])
                                          | ((unsigned long long)cvtpk(pv[c4][2], pv[c4][3]) << 32);
                    *(unsigned long long*)&Ps[half][(prow * 64 + c4 * 16 + g4 * 4) ^ pswz] = ll;
                }
                WAITLG0();
            }
            if (pre) {
                union { unsigned short u[8]; bf16x8 v; } w0;
                #pragma unroll
                for (int i2 = 0; i2 < 8; i2++) w0.u[i2] = vtmp[i2];
                *(bf16x8*)&Vt[cur ^ 1][vd * 66 + (vsb ^ (vd & 7)) * 8] = w0.v;
            }
            if (act) {
                bf16x8 pa[2];
                #pragma unroll
                for (int kk = 0; kk < 2; kk++)
                    pa[kk] = *(const bf16x8*)&Ps[half][(prow * 64 + kk * 32 + g4 * 8) ^ pswz];
                #pragma unroll
                for (int n4 = 0; n4 < 4; n4++) {
                    int d = n4 * 16 + r;
                    #pragma unroll
                    for (int kk = 0; kk < 2; kk++) {
                        bf16x8 vf = *(const bf16x8*)&Vt[cur][d * 66 + (((kk * 4 + g4) ^ (d & 7)) << 3)];
                        oacc[n4] = __builtin_amdgcn_mfma_f32_16x16x32_bf16(vf, pa[kk], oacc[n4], 0, 0, 0);
                    }
                }
            }
            __syncthreads();
        }

        float inv = 1.f / l_i;
        #pragma unroll
        for (int n4 = 0; n4 < 4; n4++) {
            unsigned long long ll = (unsigned long long)cvtpk(oacc[n4][0] * inv, oacc[n4][1] * inv)
                                  | ((unsigned long long)cvtpk(oacc[n4][2] * inv, oacc[n4][3] * inv) << 32);
            size_t oidx = ((size_t)(bb * 1024 + qrow)) * 1024 + hh * 64 + n4 * 16 + g4 * 4;
            *(unsigned long long*)&att[oidx] = ll;
        }
    }
}

// ---------------- host ----------------
extern "C" void kernel_launch(void* const* d_in, const int* in_sizes, int n_in,
                              void* d_out, int out_size, void* d_ws, size_t ws_size,
                              hipStream_t stream)
{
    const float* x     = (const float*)d_in[0];
    const float* Wq    = (const float*)d_in[1];
    const float* Wk    = (const float*)d_in[2];
    const float* Wv    = (const float*)d_in[3];
    const float* eq    = (const float*)d_in[4];
    const float* bq    = (const float*)d_in[5];
    const float* ek    = (const float*)d_in[6];
    const float* bk    = (const float*)d_in[7];
    const float* ev    = (const float*)d_in[8];
    const float* bv    = (const float*)d_in[9];
    const float* Wp    = (const float*)d_in[10];
    const float* ep    = (const float*)d_in[11];
    const float* bp    = (const float*)d_in[12];
    const float* biasp = (const float*)d_in[13];
    const float* W1    = (const float*)d_in[14];
    const float* e1    = (const float*)d_in[15];
    const float* b1    = (const float*)d_in[16];
    const float* bias1 = (const float*)d_in[17];
    const float* W2    = (const float*)d_in[18];
    const float* e2    = (const float*)d_in[19];
    const float* b2    = (const float*)d_in[20];
    const float* bias2 = (const float*)d_in[21];
    const float* g1    = (const float*)d_in[22];
    const float* be1   = (const float*)d_in[23];
    const float* g2    = (const float*)d_in[24];
    const float* be2   = (const float*)d_in[25];

    const size_t MB = 1ull << 20;
    char* ws = (char*)d_ws;
    unsigned short* Wqkvq = (unsigned short*)(ws);            //  6 MB
    unsigned short* Wpq   = (unsigned short*)(ws + 6 * MB);   //  2 MB
    unsigned short* W1q   = (unsigned short*)(ws + 8 * MB);   //  8 MB
    unsigned short* W2q   = (unsigned short*)(ws + 16 * MB);  //  8 MB
    unsigned short* hbuf  = (unsigned short*)(ws + 24 * MB);  // 16 MB
    unsigned short* qkvb  = (unsigned short*)(ws + 40 * MB);  // 48 MB; later f (64 MB)
    unsigned short* fbuf  = qkvb;
    unsigned short* attb  = (unsigned short*)(ws + 88 * MB);  // 16 MB
    unsigned short* x2b   = (unsigned short*)(ws + 104 * MB); // 16 MB (bf16 residual)

    fused_pre_kernel<<<4096, 256, 0, stream>>>(Wq, Wk, Wv, Wp, W1, W2,
                                               eq, ek, ev, ep, e1, e2,
                                               bq, bk, bv, bp, b1, b2,
                                               Wqkvq, Wpq, W1q, W2q,
                                               x, g1, be1, hbuf);

    // QKV: [8192,3072] bf16, 128^2 8-wave gemm_bt (1536 blocks = 3 full rounds)
    gemm_bt<0><<<dim3(24, 64), 512, 0, stream>>>(hbuf, Wqkvq, 3072, 1024, nullptr, nullptr, nullptr, nullptr, qkvb);
    // attention (8-wave shared staging, supertile-paired)
    attn_kernel<<<dim3(4, 128), 512, 0, stream>>>(qkvb, attb);
    // proj + bias + residual(x fp32) -> x2b (bf16)
    gemm_bt<3><<<dim3(8, 64), 512, 0, stream>>>(attb, Wpq, 1024, 1024, biasp, x, nullptr, nullptr, x2b);
    // LN2: x2b (bf16) -> hbuf
    ln_bf_kernel<<<2048, 256, 0, stream>>>(x2b, g2, be2, hbuf);
    // FFN1: relu(h2 W1^T + b1) -> f (bf16), 256^2 8-phase
    gemm256<2><<<dim3(16, 32), 512, 0, stream>>>(hbuf, W1q, 4096, 1024, bias1, nullptr, nullptr, fbuf);
    // FFN2: f W2^T + b2 + x2b(bf16) -> out (fp32), 8-wave gemm_bt
    gemm_bt<4><<<dim3(8, 64), 512, 0, stream>>>(fbuf, W2q, 1024, 4096, bias2, nullptr, x2b, (float*)d_out, nullptr);
}